// Round 2
// baseline (1667.280 us; speedup 1.0000x reference)
//
#include <hip/hip_runtime.h>
#include <math.h>

#define N_B   8
#define C_DIM 256
#define H_DIM 128
#define W_DIM 128
#define HW    (H_DIM*W_DIM)   // 16384
#define PH    64
#define PW    64
#define PHW   (PH*PW)         // 4096
#define CC    (C_DIM*C_DIM)   // 65536
#define EPS_COV 1e-5f
#define NS_ITERS 6

__device__ inline unsigned int fenc(float f) {
    unsigned int u = __float_as_uint(f);
    return (u & 0x80000000u) ? ~u : (u | 0x80000000u);
}
__device__ inline float fdec(unsigned int u) {
    return (u & 0x80000000u) ? __uint_as_float(u & 0x7fffffffu) : __uint_as_float(~u);
}

// ---------------- pool (2x2 mean) + per-(n,c) mean + global min/max ----------------
__global__ void pool_kernel(const float* __restrict__ x, float* __restrict__ p,
                            float* __restrict__ mean, unsigned int* __restrict__ mm)
{
    int nc = blockIdx.x;        // 0..2047
    int t  = threadIdx.x;       // 0..255
    const float* xp = x + (size_t)nc * HW;
    float* pp = p + (size_t)nc * PHW;
    float lsum = 0.f, lmin = 1e30f, lmax = -1e30f;
    #pragma unroll
    for (int i = 0; i < PHW/256; ++i) {
        int pidx = i*256 + t;
        int ph = pidx >> 6, pw = pidx & 63;
        const float* r0 = xp + (size_t)(2*ph)*W_DIM + 2*pw;
        float2 a = *reinterpret_cast<const float2*>(r0);
        float2 b = *reinterpret_cast<const float2*>(r0 + W_DIM);
        float v = (a.x + a.y + b.x + b.y) * 0.25f;
        pp[pidx] = v;
        lsum += v;
        lmin = fminf(lmin, v);
        lmax = fmaxf(lmax, v);
    }
    __shared__ float ssum[256], smin[256], smax[256];
    ssum[t] = lsum; smin[t] = lmin; smax[t] = lmax;
    __syncthreads();
    for (int s = 128; s > 0; s >>= 1) {
        if (t < s) {
            ssum[t] += ssum[t+s];
            smin[t] = fminf(smin[t], smin[t+s]);
            smax[t] = fmaxf(smax[t], smax[t+s]);
        }
        __syncthreads();
    }
    if (t == 0) {
        mean[nc] = ssum[0] / (float)PHW;
        atomicMin(&mm[0], fenc(smin[0]));
        atomicMax(&mm[1], fenc(smax[0]));
    }
}

// ---------------- shared 64x64-tile fp32 GEMM core ----------------
__device__ inline void tile64(const float* __restrict__ Ab, int lda,
                              const float* __restrict__ Bb, int ldb,
                              int n, int r0, int c0, int t,
                              float (&As)[16][68], float (&Bs)[16][68],
                              float (&acc)[4][4])
{
    int tx = t & 15, ty = t >> 4;
    int lr = t >> 2, lc4 = (t & 3) * 4;
    int brow = t >> 4, bcol = (t & 15) * 4;
    for (int k0 = 0; k0 < n; k0 += 16) {
        float4 av = *reinterpret_cast<const float4*>(Ab + (size_t)(r0+lr)*lda + k0 + lc4);
        float4 bv = *reinterpret_cast<const float4*>(Bb + (size_t)(k0+brow)*ldb + c0 + bcol);
        __syncthreads();
        As[lc4+0][lr] = av.x; As[lc4+1][lr] = av.y; As[lc4+2][lr] = av.z; As[lc4+3][lr] = av.w;
        *reinterpret_cast<float4*>(&Bs[brow][bcol]) = bv;
        __syncthreads();
        #pragma unroll
        for (int kk = 0; kk < 16; ++kk) {
            float4 a4 = *reinterpret_cast<const float4*>(&As[kk][ty*4]);
            float4 b4 = *reinterpret_cast<const float4*>(&Bs[kk][tx*4]);
            float a[4] = {a4.x, a4.y, a4.z, a4.w};
            float bb[4] = {b4.x, b4.y, b4.z, b4.w};
            #pragma unroll
            for (int i = 0; i < 4; ++i)
                #pragma unroll
                for (int j = 0; j < 4; ++j)
                    acc[i][j] += a[i] * bb[j];
        }
    }
}

// ---------------- cov = (4/16383) * pc @ pc^T + eps I  (symmetric, upper blocks only) ----
__global__ void cov_kernel(const float* __restrict__ p, const float* __restrict__ mean,
                           float* __restrict__ cov)
{
    int bx = blockIdx.x, by = blockIdx.y;
    if (bx > by) return;                      // symmetry: compute upper block-triangle
    int b  = blockIdx.z;
    int c0 = bx * 64, d0 = by * 64;
    int t  = threadIdx.x;
    int tx = t & 15, ty = t >> 4;
    __shared__ float As[16][68];
    __shared__ float Bs[16][68];
    const float* pb = p + (size_t)b * C_DIM * PHW;
    const float* mb = mean + b * C_DIM;
    int lr  = t >> 2;         // 0..63
    int lc4 = (t & 3) * 4;    // 0,4,8,12
    float am = mb[c0 + lr];
    float bm = mb[d0 + lr];
    const float* aptr = pb + (size_t)(c0 + lr) * PHW + lc4;
    const float* bptr = pb + (size_t)(d0 + lr) * PHW + lc4;
    float acc[4][4] = {};
    for (int k0 = 0; k0 < PHW; k0 += 16) {
        float4 av = *reinterpret_cast<const float4*>(aptr + k0);
        float4 bv = *reinterpret_cast<const float4*>(bptr + k0);
        __syncthreads();
        As[lc4+0][lr] = av.x - am; As[lc4+1][lr] = av.y - am;
        As[lc4+2][lr] = av.z - am; As[lc4+3][lr] = av.w - am;
        Bs[lc4+0][lr] = bv.x - bm; Bs[lc4+1][lr] = bv.y - bm;
        Bs[lc4+2][lr] = bv.z - bm; Bs[lc4+3][lr] = bv.w - bm;
        __syncthreads();
        #pragma unroll
        for (int kk = 0; kk < 16; ++kk) {
            float4 a4 = *reinterpret_cast<const float4*>(&As[kk][ty*4]);
            float4 b4 = *reinterpret_cast<const float4*>(&Bs[kk][tx*4]);
            float a[4] = {a4.x, a4.y, a4.z, a4.w};
            float bb[4] = {b4.x, b4.y, b4.z, b4.w};
            #pragma unroll
            for (int i = 0; i < 4; ++i)
                #pragma unroll
                for (int j = 0; j < 4; ++j)
                    acc[i][j] += a[i] * bb[j];
        }
    }
    const float scale = 4.0f / (float)(HW - 1);
    float* cb = cov + (size_t)b * CC;
    #pragma unroll
    for (int i = 0; i < 4; ++i) {
        int ci = c0 + ty*4 + i;
        #pragma unroll
        for (int j = 0; j < 4; ++j) {
            int dj = d0 + tx*4 + j;
            float v = acc[i][j] * scale + ((ci == dj) ? EPS_COV : 0.0f);
            cb[(size_t)ci * C_DIM + dj] = v;
            cb[(size_t)dj * C_DIM + ci] = v;   // mirror (benign identical write on diag blocks)
        }
    }
}

// ---------------- trace/C per batch ----------------
__global__ void trace_kernel(const float* __restrict__ cov, float* __restrict__ cvec)
{
    int b = blockIdx.x, t = threadIdx.x;
    float v = cov[(size_t)b*CC + (size_t)t*C_DIM + t];
    __shared__ float s[256];
    s[t] = v; __syncthreads();
    for (int st = 128; st > 0; st >>= 1) {
        if (t < st) s[t] += s[t+st];
        __syncthreads();
    }
    if (t == 0) cvec[b] = s[0] / 256.0f;
}

// ---------------- NS init: Y = cov/c, Z = I ----------------
__global__ void ns_init_kernel(const float* __restrict__ cov, const float* __restrict__ cvec,
                               float* __restrict__ Y, float* __restrict__ Z)
{
    size_t idx = (size_t)blockIdx.x * 256 + threadIdx.x;
    int b  = (int)(idx >> 16);
    int ij = (int)(idx & 65535);
    float ic = 1.0f / cvec[b];
    Y[idx] = cov[idx] * ic;
    Z[idx] = ((ij >> 8) == (ij & 255)) ? 1.0f : 0.0f;
}

// ---------------- generic batched n x n GEMM: C = alpha*A@B + beta*I + gamma*Cin ----------------
__global__ void gemm_kernel(const float* __restrict__ A, int lda, long long sA,
                            const float* __restrict__ B, int ldb, long long sB,
                            float* __restrict__ C, int ldc, long long sC,
                            const float* __restrict__ Cin, int ldcin, long long sCin,
                            int n, float alpha, float beta, float gamma)
{
    int b  = blockIdx.z;
    int r0 = blockIdx.x * 64, c0 = blockIdx.y * 64;
    int t  = threadIdx.x;
    int tx = t & 15, ty = t >> 4;
    __shared__ float As[16][68];
    __shared__ float Bs[16][68];
    float acc[4][4] = {};
    tile64(A + (size_t)b*sA, lda, B + (size_t)b*sB, ldb, n, r0, c0, t, As, Bs, acc);
    float* Cb = C + (size_t)b * sC;
    #pragma unroll
    for (int i = 0; i < 4; ++i) {
        int r = r0 + ty*4 + i;
        #pragma unroll
        for (int j = 0; j < 4; ++j) {
            int c = c0 + tx*4 + j;
            float v = alpha * acc[i][j];
            if (beta != 0.0f && r == c) v += beta;
            if (gamma != 0.0f) v += gamma * Cin[(size_t)b*sCin + (size_t)r*ldcin + c];
            Cb[(size_t)r*ldc + c] = v;
        }
    }
}

// ---------------- NS pair update: Yn = Y@W, Zn = W@Z in one launch ----------------
__global__ void ns_pair_kernel(const float* __restrict__ Y, const float* __restrict__ Z,
                               const float* __restrict__ W,
                               float* __restrict__ Yn, float* __restrict__ Zn)
{
    int bz = blockIdx.z;
    int b = bz >> 1, which = bz & 1;
    const float* A = which ? W + (size_t)b*CC : Y + (size_t)b*CC;
    const float* B = which ? Z + (size_t)b*CC : W + (size_t)b*CC;
    float*       C = which ? Zn + (size_t)b*CC : Yn + (size_t)b*CC;
    int r0 = blockIdx.x * 64, c0 = blockIdx.y * 64;
    int t  = threadIdx.x;
    int tx = t & 15, ty = t >> 4;
    __shared__ float As[16][68];
    __shared__ float Bs[16][68];
    float acc[4][4] = {};
    tile64(A, 256, B, 256, 256, r0, c0, t, As, Bs, acc);
    #pragma unroll
    for (int i = 0; i < 4; ++i)
        #pragma unroll
        for (int j = 0; j < 4; ++j)
            C[(size_t)(r0+ty*4+i)*256 + c0+tx*4+j] = acc[i][j];
}

// ---------------- wm = Z / sqrt(c) ----------------
__global__ void wm_kernel(const float* __restrict__ Z, const float* __restrict__ cvec,
                          float* __restrict__ wm)
{
    size_t idx = (size_t)blockIdx.x * 256 + threadIdx.x;
    int b = (int)(idx >> 16);
    wm[idx] = Z[idx] * (1.0f / sqrtf(cvec[b]));
}

// ---------------- strict-lower-triangle stats ----------------
__global__ void tex_stats_kernel(const float* __restrict__ wm,
                                 float* __restrict__ tm, float* __restrict__ ts)
{
    int b = blockIdx.x, t = threadIdx.x;
    const float* w = wm + (size_t)b * CC;
    float sum = 0.f, sumsq = 0.f;
    for (int flat = t; flat < CC; flat += 256) {
        int i = flat >> 8, j = flat & 255;
        if (i > j) {
            float v = w[flat];
            sum += v; sumsq += v * v;
        }
    }
    __shared__ float s1[256], s2[256];
    s1[t] = sum; s2[t] = sumsq;
    __syncthreads();
    for (int st = 128; st > 0; st >>= 1) {
        if (t < st) { s1[t] += s1[t+st]; s2[t] += s2[t+st]; }
        __syncthreads();
    }
    if (t == 0) {
        float m = s1[0] / 32640.0f;
        // sum over ALL C*C entries of (wm_trid - m)^2, zeros contribute m^2, divisor num_tri
        float var = (s2[0] - 2.0f*m*s1[0] + m*m*65536.0f) / 32640.0f;
        tm[b] = m;
        ts[b] = sqrtf(fmaxf(var, 0.0f));
    }
}

// ---------------- assemble wm_s ----------------
__global__ void assemble_kernel(const float* __restrict__ wm, const float* __restrict__ eps,
                                const float* __restrict__ tm, const float* __restrict__ ts,
                                float* __restrict__ wms)
{
    size_t idx = (size_t)blockIdx.x * 256 + threadIdx.x;
    int b  = (int)(idx >> 16);
    int ij = (int)(idx & 65535);
    int i = ij >> 8, j = ij & 255;
    float v;
    if (i == j) {
        v = wm[idx];
    } else {
        int lo = min(i, j), hi = max(i, j);
        v = tm[b] + 10.0f * ts[b] * eps[(size_t)b*CC + (size_t)lo*256 + hi];
    }
    wms[idx] = v;
}

// ---------------- 128x128 Gauss-Jordan inverse (partial pivoting, static LDS) ----------------
__global__ __launch_bounds__(1024, 1)
void gj_inv128_kernel(const float* __restrict__ Ain, int lda, long long sA,
                      float* __restrict__ Out, int ldo, long long sO)
{
    const int LD = 257;
    __shared__ float aug[128 * LD];   // 131,584 B (gfx950 LDS = 160 KiB)
    __shared__ int spiv;
    int b  = blockIdx.x;
    int t  = threadIdx.x;            // 0..1023
    int tx = t & 255, ty = t >> 8;   // col, row-group
    const float* Ab = Ain + (size_t)b * sA;
    #pragma unroll
    for (int i = 0; i < 32; ++i) {
        int r = ty + 4*i;
        float v;
        if (tx < 128) v = Ab[(size_t)r*lda + tx];
        else          v = ((tx - 128) == r) ? 1.0f : 0.0f;
        aug[r*LD + tx] = v;
    }
    __syncthreads();
    for (int k = 0; k < 128; ++k) {
        if (t < 64) {
            float v1 = (t >= k) ? fabsf(aug[t*LD + k]) : -1.0f;
            int   i1 = t;
            int   r2 = t + 64;
            float v2 = (r2 >= k) ? fabsf(aug[r2*LD + k]) : -1.0f;
            if (v2 > v1) { v1 = v2; i1 = r2; }
            #pragma unroll
            for (int m = 32; m; m >>= 1) {
                float ov = __shfl_xor(v1, m);
                int   oi = __shfl_xor(i1, m);
                if (ov > v1) { v1 = ov; i1 = oi; }
            }
            if (t == 0) spiv = i1;
        }
        __syncthreads();
        int piv = spiv;
        if (piv != k) {                 // uniform branch
            if (ty == 0) {
                float tmp = aug[k*LD + tx];
                aug[k*LD + tx] = aug[piv*LD + tx];
                aug[piv*LD + tx] = tmp;
            }
            __syncthreads();
        }
        float pv = aug[k*LD + k];
        float rp = 1.0f / pv;
        __syncthreads();
        if (ty == 0) aug[k*LD + tx] *= rp;
        __syncthreads();
        float pr = aug[k*LD + tx];
        float f[32];
        #pragma unroll
        for (int i = 0; i < 32; ++i) {
            int r = ty + 4*i;
            f[i] = aug[r*LD + k];
        }
        __syncthreads();
        #pragma unroll
        for (int i = 0; i < 32; ++i) {
            int r = ty + 4*i;
            if (r != k) aug[r*LD + tx] -= f[i] * pr;
        }
        __syncthreads();
    }
    float* Ob = Out + (size_t)b * sO;
    #pragma unroll
    for (int i = 0; i < 32; ++i) {
        int r = ty + 4*i;
        if (tx >= 128) Ob[(size_t)r*ldo + (tx - 128)] = aug[r*LD + tx];
    }
}

// ------- fused: target-pool GEMM (M @ (p-mean)) + upsample + clip + HH + write out -------
__global__ void target_kernel(const float* __restrict__ M, const float* __restrict__ p,
                              const float* __restrict__ mean, const float* __restrict__ x,
                              const unsigned int* __restrict__ mm, float* __restrict__ out)
{
    int b  = blockIdx.z;
    int c0 = blockIdx.x * 64;     // channel block
    int ph = blockIdx.y;          // pooled row (block covers pooled flat [ph*64, ph*64+64))
    int h0 = ph * 64;
    int t  = threadIdx.x;
    int tx = t & 15, ty = t >> 4;
    __shared__ float As[16][68];
    __shared__ float Bs[16][68];
    __shared__ float accS[64][66];
    const float* Mb = M + (size_t)b * CC;
    const float* pb = p + (size_t)b * C_DIM * PHW;
    const float* mb = mean + b * C_DIM;
    int lr   = t >> 2;
    int lc4  = (t & 3) * 4;
    int brow = t >> 4;
    int bcol = (t & 15) * 4;
    float acc[4][4] = {};
    for (int k0 = 0; k0 < C_DIM; k0 += 16) {
        float4 av = *reinterpret_cast<const float4*>(Mb + (size_t)(c0+lr)*C_DIM + k0 + lc4);
        float  bm = mb[k0 + brow];
        float4 bv = *reinterpret_cast<const float4*>(pb + (size_t)(k0+brow)*PHW + h0 + bcol);
        bv.x -= bm; bv.y -= bm; bv.z -= bm; bv.w -= bm;
        __syncthreads();
        As[lc4+0][lr] = av.x; As[lc4+1][lr] = av.y; As[lc4+2][lr] = av.z; As[lc4+3][lr] = av.w;
        *reinterpret_cast<float4*>(&Bs[brow][bcol]) = bv;
        __syncthreads();
        #pragma unroll
        for (int kk = 0; kk < 16; ++kk) {
            float4 a4 = *reinterpret_cast<const float4*>(&As[kk][ty*4]);
            float4 b4 = *reinterpret_cast<const float4*>(&Bs[kk][tx*4]);
            float a[4] = {a4.x, a4.y, a4.z, a4.w};
            float bb[4] = {b4.x, b4.y, b4.z, b4.w};
            #pragma unroll
            for (int i = 0; i < 4; ++i)
                #pragma unroll
                for (int j = 0; j < 4; ++j)
                    acc[i][j] += a[i] * bb[j];
        }
    }
    __syncthreads();
    #pragma unroll
    for (int i = 0; i < 4; ++i)
        *reinterpret_cast<float4*>(&accS[ty*4+i][tx*4]) =
            make_float4(acc[i][0], acc[i][1], acc[i][2], acc[i][3]);
    __syncthreads();
    // epilogue: coalesced upsample+clip+HH. wave lanes sweep 128 output cols.
    float mn = fdec(mm[0]);
    float mx = fdec(mm[1]);
    int lane_ch = t >> 5;           // 0..7
    int col4 = (t & 31) * 4;        // 0..124  (4 output cols = 2 pooled pixels)
    int pw2 = (t & 31) * 2;
    #pragma unroll
    for (int cc8 = 0; cc8 < 64; cc8 += 8) {
        int ch  = cc8 + lane_ch;
        int gch = c0 + ch;
        float me = mb[gch];
        float2 av = *reinterpret_cast<const float2*>(&accS[ch][pw2]);
        float t0 = fminf(fmaxf(av.x + me, mn), mx);
        float t1 = fminf(fmaxf(av.y + me, mn), mx);
        float2 pv = *reinterpret_cast<const float2*>(
            pb + (size_t)gch * PHW + h0 + pw2);
        size_t xbase = (((size_t)b * C_DIM + gch) * H_DIM + 2*ph) * W_DIM + col4;
        #pragma unroll
        for (int row = 0; row < 2; ++row) {
            float4 xv = *reinterpret_cast<const float4*>(x + xbase + row*W_DIM);
            float4 o;
            o.x = xv.x - pv.x + t0;
            o.y = xv.y - pv.x + t0;
            o.z = xv.z - pv.y + t1;
            o.w = xv.w - pv.y + t1;
            *reinterpret_cast<float4*>(out + xbase + row*W_DIM) = o;
        }
    }
}

extern "C" void kernel_launch(void* const* d_in, const int* in_sizes, int n_in,
                              void* d_out, int out_size, void* d_ws, size_t ws_size,
                              hipStream_t stream)
{
    const float* x   = (const float*)d_in[0];
    const float* eps = (const float*)d_in[1];
    float* out = (float*)d_out;
    float* w = (float*)d_ws;

    // ---- workspace layout (aliased; ~12.06M floats = 48.3 MB) ----
    size_t o = 0;
    float* p    = w + o; o += (size_t)N_B * C_DIM * PHW;  // 8,388,608
    float* bufA = w + o; o += (size_t)N_B * CC;  // cov -> wms
    float* bufY = w + o; o += (size_t)N_B * CC;  // Y   -> Minv
    float* bufZ = w + o; o += (size_t)N_B * CC;  // Z   -> Rb
    float* bufY2= w + o; o += (size_t)N_B * CC;  // Y2  -> Minv2
    float* bufZ2= w + o; o += (size_t)N_B * CC;  // Z2  -> Mm
    float* bufW = w + o; o += (size_t)N_B * CC;  // W   -> {invA11,T1,T2,Sm}
    float* wmb  = w + o; o += (size_t)N_B * CC;
    float* meanb= w + o; o += N_B * C_DIM;
    float* cvec = w + o; o += N_B;
    float* tm   = w + o; o += N_B;
    float* ts   = w + o; o += N_B;
    unsigned int* mmx = (unsigned int*)(w + o); o += 2;

    float* cov  = bufA;
    float* wms  = bufA;
    float* Minv = bufY;
    float* Rb   = bufZ;
    float* Minv2= bufY2;
    float* Mm   = bufZ2;
    float* invA11 = bufW;
    float* T1     = bufW + (size_t)N_B * 128 * 128;
    float* T2     = bufW + (size_t)N_B * 128 * 128 * 2;
    float* Sm     = bufW + (size_t)N_B * 128 * 128 * 3;

    // init min/max holders: min := 0xFFFFFFFF (encoded +inf-ish), max := 0x00000000
    hipMemsetAsync(mmx,     0xFF, 4, stream);
    hipMemsetAsync(mmx + 1, 0x00, 4, stream);

    pool_kernel<<<N_B * C_DIM, 256, 0, stream>>>(x, p, meanb, mmx);
    cov_kernel<<<dim3(4, 4, N_B), 256, 0, stream>>>(p, meanb, cov);
    trace_kernel<<<N_B, 256, 0, stream>>>(cov, cvec);
    ns_init_kernel<<<2048, 256, 0, stream>>>(cov, cvec, bufY, bufZ);

    const long long S  = (long long)CC;
    const long long Sh = 128LL * 128LL;
    float* Yc = bufY; float* Zc = bufZ; float* Yn = bufY2; float* Zn = bufZ2;
    for (int it = 0; it < NS_ITERS; ++it) {
        // W = 1.5 I - 0.5 * Z @ Y
        gemm_kernel<<<dim3(4,4,N_B), 256, 0, stream>>>(Zc,256,S, Yc,256,S, bufW,256,S,
                                                       nullptr,0,0, 256, -0.5f, 1.5f, 0.0f);
        // Y' = Y @ W ; Z' = W @ Z  (one launch)
        ns_pair_kernel<<<dim3(4,4,2*N_B), 256, 0, stream>>>(Yc, Zc, bufW, Yn, Zn);
        float* tmp;
        tmp = Yc; Yc = Yn; Yn = tmp;
        tmp = Zc; Zc = Zn; Zn = tmp;
    }
    // NS_ITERS even => Zc == bufZ, Yc == bufY here.
    wm_kernel<<<2048, 256, 0, stream>>>(Zc, cvec, wmb);
    tex_stats_kernel<<<N_B, 256, 0, stream>>>(wmb, tm, ts);
    assemble_kernel<<<2048, 256, 0, stream>>>(wmb, eps, tm, ts, wms);  // wms aliases cov (dead)

    // ---- Schur-complement inverse of wms (2x2 blocks of 128) ----
    gj_inv128_kernel<<<N_B, 1024, 0, stream>>>(wms, 256, S, invA11, 128, Sh);
    // T1 = invA11 @ A12
    gemm_kernel<<<dim3(2,2,N_B), 256, 0, stream>>>(invA11,128,Sh, wms+128,256,S, T1,128,Sh,
                                                   nullptr,0,0, 128, 1.0f, 0.0f, 0.0f);
    // T2 = A21 @ invA11
    gemm_kernel<<<dim3(2,2,N_B), 256, 0, stream>>>(wms+128*256,256,S, invA11,128,Sh, T2,128,Sh,
                                                   nullptr,0,0, 128, 1.0f, 0.0f, 0.0f);
    // Sm = A22 - A21 @ T1
    gemm_kernel<<<dim3(2,2,N_B), 256, 0, stream>>>(wms+128*256,256,S, T1,128,Sh, Sm,128,Sh,
                                                   wms+128*256+128,256,S, 128, -1.0f, 0.0f, 1.0f);
    // invS -> Minv22
    gj_inv128_kernel<<<N_B, 1024, 0, stream>>>(Sm, 128, Sh, Minv+128*256+128, 256, S);
    // M12 = -T1 @ invS
    gemm_kernel<<<dim3(2,2,N_B), 256, 0, stream>>>(T1,128,Sh, Minv+128*256+128,256,S, Minv+128,256,S,
                                                   nullptr,0,0, 128, -1.0f, 0.0f, 0.0f);
    // M21 = -invS @ T2
    gemm_kernel<<<dim3(2,2,N_B), 256, 0, stream>>>(Minv+128*256+128,256,S, T2,128,Sh, Minv+128*256,256,S,
                                                   nullptr,0,0, 128, -1.0f, 0.0f, 0.0f);
    // M11 = invA11 - T1 @ M21
    gemm_kernel<<<dim3(2,2,N_B), 256, 0, stream>>>(T1,128,Sh, Minv+128*256,256,S, Minv,256,S,
                                                   invA11,128,Sh, 128, -1.0f, 0.0f, 1.0f);
    // ---- one Newton refinement: Minv2 = Minv (2I - wms Minv) ----
    gemm_kernel<<<dim3(4,4,N_B), 256, 0, stream>>>(wms,256,S, Minv,256,S, Rb,256,S,
                                                   nullptr,0,0, 256, -1.0f, 2.0f, 0.0f);
    gemm_kernel<<<dim3(4,4,N_B), 256, 0, stream>>>(Minv,256,S, Rb,256,S, Minv2,256,S,
                                                   nullptr,0,0, 256, 1.0f, 0.0f, 0.0f);
    // M = Minv2 @ wm
    gemm_kernel<<<dim3(4,4,N_B), 256, 0, stream>>>(Minv2,256,S, wmb,256,S, Mm,256,S,
                                                   nullptr,0,0, 256, 1.0f, 0.0f, 0.0f);

    // fused target GEMM + upsample + clip + HH + output
    target_kernel<<<dim3(4, 64, N_B), 256, 0, stream>>>(Mm, p, meanb, x, mmx, out);

    (void)in_sizes; (void)n_in; (void)out_size; (void)ws_size;
}

// Round 4
// 1162.270 us; speedup vs baseline: 1.4345x; 1.4345x over previous
//
#include <hip/hip_runtime.h>
#include <math.h>

#define N_B   8
#define C_DIM 256
#define H_DIM 128
#define W_DIM 128
#define HW    (H_DIM*W_DIM)   // 16384
#define PH    64
#define PW    64
#define PHW   (PH*PW)         // 4096
#define CC    (C_DIM*C_DIM)   // 65536
#define EPS_COV 1e-5f
#define COVSCALE (4.0f / 16383.0f)
#define NBGJ 16

__device__ inline unsigned int fenc(float f) {
    unsigned int u = __float_as_uint(f);
    return (u & 0x80000000u) ? ~u : (u | 0x80000000u);
}
__device__ inline float fdec(unsigned int u) {
    return (u & 0x80000000u) ? __uint_as_float(u & 0x7fffffffu) : __uint_as_float(~u);
}

// ---------------- pool (2x2 mean) + per-(n,c) sum/sumsq + global min/max ----------------
__global__ void pool_kernel(const float* __restrict__ x, float* __restrict__ p,
                            float* __restrict__ mean, float* __restrict__ sqb,
                            unsigned int* __restrict__ mm)
{
    int nc = blockIdx.x;        // 0..2047
    int t  = threadIdx.x;       // 0..255
    const float* xp = x + (size_t)nc * HW;
    float* pp = p + (size_t)nc * PHW;
    float lsum = 0.f, lsq = 0.f, lmin = 1e30f, lmax = -1e30f;
    #pragma unroll
    for (int i = 0; i < PHW/256; ++i) {
        int pidx = i*256 + t;
        int ph = pidx >> 6, pw = pidx & 63;
        const float* r0 = xp + (size_t)(2*ph)*W_DIM + 2*pw;
        float2 a = *reinterpret_cast<const float2*>(r0);
        float2 b = *reinterpret_cast<const float2*>(r0 + W_DIM);
        float v = (a.x + a.y + b.x + b.y) * 0.25f;
        pp[pidx] = v;
        lsum += v;
        lsq  += v * v;
        lmin = fminf(lmin, v);
        lmax = fmaxf(lmax, v);
    }
    __shared__ float ssum[256], ssq[256], smin[256], smax[256];
    ssum[t] = lsum; ssq[t] = lsq; smin[t] = lmin; smax[t] = lmax;
    __syncthreads();
    for (int s = 128; s > 0; s >>= 1) {
        if (t < s) {
            ssum[t] += ssum[t+s];
            ssq[t]  += ssq[t+s];
            smin[t] = fminf(smin[t], smin[t+s]);
            smax[t] = fmaxf(smax[t], smax[t+s]);
        }
        __syncthreads();
    }
    if (t == 0) {
        mean[nc] = ssum[0] / (float)PHW;
        sqb[nc]  = ssq[0];
        atomicMin(&mm[0], fenc(smin[0]));
        atomicMax(&mm[1], fenc(smax[0]));
    }
}

// ---------------- cvec[b] = mean_c(diag cov) (incl eps); scv = 1/sqrt ----------------
__global__ void cvec_kernel(const float* __restrict__ mean, const float* __restrict__ sqb,
                            float* __restrict__ cvec, float* __restrict__ scv)
{
    int b = blockIdx.x, t = threadIdx.x;
    float m = mean[b*C_DIM + t];
    float s2 = sqb[b*C_DIM + t];
    float cv = COVSCALE * (s2 - (float)PHW * m * m) + EPS_COV;
    __shared__ float s[256];
    s[t] = cv; __syncthreads();
    for (int st = 128; st > 0; st >>= 1) {
        if (t < st) s[t] += s[t+st];
        __syncthreads();
    }
    if (t == 0) {
        float c = s[0] / 256.0f;
        cvec[b] = c;
        scv[b] = 1.0f / sqrtf(c);
    }
}

// ---------------- cov partial: raw pc@pc^T over a K-slice (symmetric blocks) ----------
__global__ void cov_part_kernel(const float* __restrict__ p, const float* __restrict__ mean,
                                float* __restrict__ c0p, float* __restrict__ c1p,
                                float* __restrict__ c2p, float* __restrict__ c3p)
{
    int bx = blockIdx.x, by = blockIdx.y;
    if (bx > by) return;                      // symmetry
    int bz = blockIdx.z;
    int b  = bz >> 2, ks = bz & 3;
    float* covp = (ks == 0) ? c0p : (ks == 1) ? c1p : (ks == 2) ? c2p : c3p;
    int c0 = bx * 64, d0 = by * 64;
    int t  = threadIdx.x;
    int tx = t & 15, ty = t >> 4;
    __shared__ float As[16][68];
    __shared__ float Bs[16][68];
    const float* pb = p + (size_t)b * C_DIM * PHW;
    const float* mb = mean + b * C_DIM;
    int lr  = t >> 2;
    int lc4 = (t & 3) * 4;
    float am = mb[c0 + lr];
    float bm = mb[d0 + lr];
    const float* aptr = pb + (size_t)(c0 + lr) * PHW + ks*1024 + lc4;
    const float* bptr = pb + (size_t)(d0 + lr) * PHW + ks*1024 + lc4;
    float acc[4][4] = {};
    for (int k0 = 0; k0 < 1024; k0 += 16) {
        float4 av = *reinterpret_cast<const float4*>(aptr + k0);
        float4 bv = *reinterpret_cast<const float4*>(bptr + k0);
        __syncthreads();
        As[lc4+0][lr] = av.x - am; As[lc4+1][lr] = av.y - am;
        As[lc4+2][lr] = av.z - am; As[lc4+3][lr] = av.w - am;
        Bs[lc4+0][lr] = bv.x - bm; Bs[lc4+1][lr] = bv.y - bm;
        Bs[lc4+2][lr] = bv.z - bm; Bs[lc4+3][lr] = bv.w - bm;
        __syncthreads();
        #pragma unroll
        for (int kk = 0; kk < 16; ++kk) {
            float4 a4 = *reinterpret_cast<const float4*>(&As[kk][ty*4]);
            float4 b4 = *reinterpret_cast<const float4*>(&Bs[kk][tx*4]);
            float a[4] = {a4.x, a4.y, a4.z, a4.w};
            float bb[4] = {b4.x, b4.y, b4.z, b4.w};
            #pragma unroll
            for (int i = 0; i < 4; ++i)
                #pragma unroll
                for (int j = 0; j < 4; ++j)
                    acc[i][j] += a[i] * bb[j];
        }
    }
    float* cb = covp + (size_t)b * CC;
    #pragma unroll
    for (int i = 0; i < 4; ++i) {
        int ci = c0 + ty*4 + i;
        #pragma unroll
        for (int j = 0; j < 4; ++j) {
            int dj = d0 + tx*4 + j;
            cb[(size_t)ci * C_DIM + dj] = acc[i][j];
            cb[(size_t)dj * C_DIM + ci] = acc[i][j];
        }
    }
}

// ---------------- combine partials -> Y0 = cov/c, W0 = 1.5I - 0.5 Y0 ----------------
__global__ void combine_kernel(const float* __restrict__ c0p, const float* __restrict__ c1p,
                               const float* __restrict__ c2p, const float* __restrict__ c3p,
                               const float* __restrict__ cvec,
                               float* __restrict__ Y, float* __restrict__ W0)
{
    size_t idx = (size_t)blockIdx.x * 256 + threadIdx.x;
    int b  = (int)(idx >> 16);
    int ij = (int)(idx & 65535);
    int diag = ((ij >> 8) == (ij & 255));
    float s = (c0p[idx] + c1p[idx] + c2p[idx] + c3p[idx]) * COVSCALE;
    float covv = s + (diag ? EPS_COV : 0.0f);
    float y = covv * (1.0f / cvec[b]);
    Y[idx] = y;
    W0[idx] = (diag ? 1.5f : 0.0f) - 0.5f * y;
}

// ---------------- shared 64x64-tile fp32 GEMM core ----------------
__device__ inline void tile64(const float* __restrict__ Ab, int lda,
                              const float* __restrict__ Bb, int ldb,
                              int n, int r0, int c0, int t,
                              float (&As)[16][68], float (&Bs)[16][68],
                              float (&acc)[4][4])
{
    int tx = t & 15, ty = t >> 4;
    int lr = t >> 2, lc4 = (t & 3) * 4;
    int brow = t >> 4, bcol = (t & 15) * 4;
    for (int k0 = 0; k0 < n; k0 += 16) {
        float4 av = *reinterpret_cast<const float4*>(Ab + (size_t)(r0+lr)*lda + k0 + lc4);
        float4 bv = *reinterpret_cast<const float4*>(Bb + (size_t)(k0+brow)*ldb + c0 + bcol);
        __syncthreads();
        As[lc4+0][lr] = av.x; As[lc4+1][lr] = av.y; As[lc4+2][lr] = av.z; As[lc4+3][lr] = av.w;
        *reinterpret_cast<float4*>(&Bs[brow][bcol]) = bv;
        __syncthreads();
        #pragma unroll
        for (int kk = 0; kk < 16; ++kk) {
            float4 a4 = *reinterpret_cast<const float4*>(&As[kk][ty*4]);
            float4 b4 = *reinterpret_cast<const float4*>(&Bs[kk][tx*4]);
            float a[4] = {a4.x, a4.y, a4.z, a4.w};
            float bb[4] = {b4.x, b4.y, b4.z, b4.w};
            #pragma unroll
            for (int i = 0; i < 4; ++i)
                #pragma unroll
                for (int j = 0; j < 4; ++j)
                    acc[i][j] += a[i] * bb[j];
        }
    }
}

// --------- generic batched n x n GEMM: C = alpha*alphav[b]*A@B + beta*I + gamma*Cin ---------
__global__ void gemm_kernel(const float* __restrict__ A, int lda, long long sA,
                            const float* __restrict__ B, int ldb, long long sB,
                            float* __restrict__ C, int ldc, long long sC,
                            const float* __restrict__ Cin, int ldcin, long long sCin,
                            const float* __restrict__ alphav,
                            int n, float alpha, float beta, float gamma)
{
    int b  = blockIdx.z;
    int r0 = blockIdx.x * 64, c0 = blockIdx.y * 64;
    int t  = threadIdx.x;
    int tx = t & 15, ty = t >> 4;
    __shared__ float As[16][68];
    __shared__ float Bs[16][68];
    float acc[4][4] = {};
    tile64(A + (size_t)b*sA, lda, B + (size_t)b*sB, ldb, n, r0, c0, t, As, Bs, acc);
    float al = alpha * (alphav ? alphav[b] : 1.0f);
    float* Cb = C + (size_t)b * sC;
    #pragma unroll
    for (int i = 0; i < 4; ++i) {
        int r = r0 + ty*4 + i;
        #pragma unroll
        for (int j = 0; j < 4; ++j) {
            int c = c0 + tx*4 + j;
            float v = al * acc[i][j];
            if (beta != 0.0f && r == c) v += beta;
            if (gamma != 0.0f) v += gamma * Cin[(size_t)b*sCin + (size_t)r*ldcin + c];
            Cb[(size_t)r*ldc + c] = v;
        }
    }
}

// ---------------- NS pair update: Yn = Y@W, Zn = W@Z in one launch ----------------
__global__ void ns_pair_kernel(const float* __restrict__ Y, const float* __restrict__ Z,
                               const float* __restrict__ W,
                               float* __restrict__ Yn, float* __restrict__ Zn)
{
    int bz = blockIdx.z;
    int b = bz >> 1, which = bz & 1;
    const float* A = which ? W + (size_t)b*CC : Y + (size_t)b*CC;
    const float* B = which ? Z + (size_t)b*CC : W + (size_t)b*CC;
    float*       C = which ? Zn + (size_t)b*CC : Yn + (size_t)b*CC;
    int r0 = blockIdx.x * 64, c0 = blockIdx.y * 64;
    int t  = threadIdx.x;
    int tx = t & 15, ty = t >> 4;
    __shared__ float As[16][68];
    __shared__ float Bs[16][68];
    float acc[4][4] = {};
    tile64(A, 256, B, 256, 256, r0, c0, t, As, Bs, acc);
    #pragma unroll
    for (int i = 0; i < 4; ++i)
        #pragma unroll
        for (int j = 0; j < 4; ++j)
            C[(size_t)(r0+ty*4+i)*256 + c0+tx*4+j] = acc[i][j];
}

// ---------------- strict-lower-triangle stats of wm = scv[b]*Z ----------------
__global__ void tex_stats_kernel(const float* __restrict__ Zf, const float* __restrict__ scv,
                                 float* __restrict__ tm, float* __restrict__ ts)
{
    int b = blockIdx.x, t = threadIdx.x;
    const float* w = Zf + (size_t)b * CC;
    float s = scv[b];
    float sum = 0.f, sumsq = 0.f;
    for (int flat = t; flat < CC; flat += 256) {
        int i = flat >> 8, j = flat & 255;
        if (i > j) {
            float v = w[flat] * s;
            sum += v; sumsq += v * v;
        }
    }
    __shared__ float s1[256], s2[256];
    s1[t] = sum; s2[t] = sumsq;
    __syncthreads();
    for (int st = 128; st > 0; st >>= 1) {
        if (t < st) { s1[t] += s1[t+st]; s2[t] += s2[t+st]; }
        __syncthreads();
    }
    if (t == 0) {
        float m = s1[0] / 32640.0f;
        float var = (s2[0] - 2.0f*m*s1[0] + m*m*65536.0f) / 32640.0f;
        tm[b] = m;
        ts[b] = sqrtf(fmaxf(var, 0.0f));
    }
}

// ---------------- assemble wm_s (diag from wm = scv*Z) ----------------
__global__ void assemble_kernel(const float* __restrict__ Zf, const float* __restrict__ scv,
                                const float* __restrict__ eps,
                                const float* __restrict__ tm, const float* __restrict__ ts,
                                float* __restrict__ wms)
{
    size_t idx = (size_t)blockIdx.x * 256 + threadIdx.x;
    int b  = (int)(idx >> 16);
    int ij = (int)(idx & 65535);
    int i = ij >> 8, j = ij & 255;
    float v;
    if (i == j) {
        v = Zf[idx] * scv[b];
    } else {
        int lo = min(i, j), hi = max(i, j);
        v = tm[b] + 10.0f * ts[b] * eps[(size_t)b*CC + (size_t)lo*256 + hi];
    }
    wms[idx] = v;
}

// ---- 128x128 blocked Gauss-Jordan inverse, virtual pivoting, registers-resident ----
// Panel of 16: sequential GJ on a 128x16 LDS copy tracks composed operator G
// (confined to the 16 pivot columns); trailing rank-16 update A += G*R in regs.
// inv[k,:] = RightHalf[p_k,:]  (virtual-pivot row relabeling).
__global__ __launch_bounds__(256, 1)
void gj_inv128_kernel(const float* __restrict__ Ain, int lda, long long sA,
                      float* __restrict__ Out, int ldo, long long sO)
{
    __shared__ float Pc[2][128][NBGJ + 1];
    __shared__ float Gs[2][128][NBGJ + 1];
    __shared__ float Rs[NBGJ][256];
    __shared__ int   pivots[NBGJ];
    __shared__ int   rowdest[128];
    __shared__ int   used[128];
    __shared__ float sh_rp;
    __shared__ int   sh_p;

    int b = blockIdx.x;
    int t = threadIdx.x;          // 0..255
    int q = t & 15;               // strided col ownership: cols {q, q+16, ..., q+240}
    int rg = t >> 4;              // rows rg*8 .. rg*8+7
    const float* Ab = Ain + (size_t)b * sA;

    float Areg[8][16];
    #pragma unroll
    for (int rr = 0; rr < 8; ++rr) {
        int r = rg*8 + rr;
        #pragma unroll
        for (int cc = 0; cc < 16; ++cc) {
            int c = q + cc*16;
            Areg[rr][cc] = (c < 128) ? Ab[(size_t)r*lda + c]
                                     : ((c - 128 == r) ? 1.0f : 0.0f);
        }
    }
    if (t < 128) used[t] = 0;
    __syncthreads();

    for (int pb = 0; pb < 8; ++pb) {
        // dump panel columns [16*pb, 16*pb+16): this thread's col at cc==pb is 16*pb+q -> j=q
        #pragma unroll
        for (int rr = 0; rr < 8; ++rr) {
            float val = 0.f;
            #pragma unroll
            for (int cc = 0; cc < 16; ++cc)
                if (cc == pb) val = Areg[rr][cc];
            Pc[0][rg*8 + rr][q] = val;
        }
        __syncthreads();

        for (int j = 0; j < NBGJ; ++j) {
            int cur = j & 1;
            if (t < 64) {
                float v1 = used[t]    ? -1.f : fabsf(Pc[cur][t][j]);
                float v2 = used[t+64] ? -1.f : fabsf(Pc[cur][t+64][j]);
                int i1 = t;
                if (v2 > v1) { v1 = v2; i1 = t + 64; }
                #pragma unroll
                for (int m = 32; m; m >>= 1) {
                    float ov = __shfl_xor(v1, m);
                    int   oi = __shfl_xor(i1, m);
                    if (ov > v1) { v1 = ov; i1 = oi; }
                }
                if (t == 0) {
                    sh_p = i1;
                    sh_rp = 1.0f / Pc[cur][i1][j];
                    pivots[j] = i1;
                    rowdest[i1] = pb*NBGJ + j;
                    used[i1] = 1;
                }
            }
            __syncthreads();
            if (t < 128) {
                int p = sh_p; float rp = sh_rp;
                int r = t;
                float f = Pc[cur][r][j];
                float v = (r == p) ? (rp - 1.0f) : (-f * rp);
                for (int jj = 0; jj < NBGJ; ++jj)
                    Pc[cur^1][r][jj] = Pc[cur][r][jj] + v * Pc[cur][p][jj];
                for (int jj = 0; jj < j; ++jj)
                    Gs[cur^1][r][jj] = Gs[cur][r][jj] + v * Gs[cur][p][jj];
                Gs[cur^1][r][j] = v;
            }
            __syncthreads();
        }
        // 16 steps -> final G landed in buffer 0 (j=15 wrote cur^1 = 0)

        // gather OLD pivot rows (pre-panel register values) into Rs
        for (int j = 0; j < NBGJ; ++j) {
            int p = pivots[j];
            if ((p >> 3) == rg) {
                #pragma unroll
                for (int rr = 0; rr < 8; ++rr)
                    if ((p & 7) == rr) {
                        #pragma unroll
                        for (int cc = 0; cc < 16; ++cc)
                            Rs[j][q + cc*16] = Areg[rr][cc];
                    }
            }
        }
        __syncthreads();

        // trailing rank-16 update: A[r,c] += sum_j G[r,j] * R[j,c]  (all 256 cols)
        for (int j = 0; j < NBGJ; ++j) {
            float rv[16];
            #pragma unroll
            for (int cc = 0; cc < 16; ++cc) rv[cc] = Rs[j][q + cc*16];
            #pragma unroll
            for (int rr = 0; rr < 8; ++rr) {
                float g = Gs[0][rg*8 + rr][j];
                #pragma unroll
                for (int cc = 0; cc < 16; ++cc)
                    Areg[rr][cc] = fmaf(g, rv[cc], Areg[rr][cc]);
            }
        }
        __syncthreads();
    }

    float* Ob = Out + (size_t)b * sO;
    #pragma unroll
    for (int rr = 0; rr < 8; ++rr) {
        int r = rg*8 + rr;
        int dest = rowdest[r];
        #pragma unroll
        for (int cc = 8; cc < 16; ++cc) {
            int c = q + cc*16;            // 128..255
            Ob[(size_t)dest*ldo + (c - 128)] = Areg[rr][cc];
        }
    }
}

// ---------------- M21 = M12^T (batched 128x128 transpose, In/Out ld=256) ----------------
__global__ void transpose128_kernel(const float* __restrict__ In, float* __restrict__ Outp)
{
    __shared__ float tile[16][17];
    int b = blockIdx.z;
    int r0 = blockIdx.y * 16, c0 = blockIdx.x * 16;
    int t = threadIdx.x;
    int tx = t & 15, ty = t >> 4;
    tile[ty][tx] = In[(size_t)b*CC + (size_t)(r0+ty)*256 + c0+tx];
    __syncthreads();
    Outp[(size_t)b*CC + (size_t)(c0+ty)*256 + r0+tx] = tile[tx][ty];
}

// ------- fused: target-pool GEMM (M @ (p-mean)) + upsample + clip + HH + write out -------
__global__ void target_kernel(const float* __restrict__ M, const float* __restrict__ p,
                              const float* __restrict__ mean, const float* __restrict__ x,
                              const unsigned int* __restrict__ mm, float* __restrict__ out)
{
    int b  = blockIdx.z;
    int c0 = blockIdx.x * 64;     // channel block
    int ph = blockIdx.y;          // pooled row
    int h0 = ph * 64;
    int t  = threadIdx.x;
    int tx = t & 15, ty = t >> 4;
    __shared__ float As[16][68];
    __shared__ float Bs[16][68];
    __shared__ float accS[64][66];
    const float* Mb = M + (size_t)b * CC;
    const float* pb = p + (size_t)b * C_DIM * PHW;
    const float* mb = mean + b * C_DIM;
    int lr   = t >> 2;
    int lc4  = (t & 3) * 4;
    int brow = t >> 4;
    int bcol = (t & 15) * 4;
    float acc[4][4] = {};
    for (int k0 = 0; k0 < C_DIM; k0 += 16) {
        float4 av = *reinterpret_cast<const float4*>(Mb + (size_t)(c0+lr)*C_DIM + k0 + lc4);
        float  bm = mb[k0 + brow];
        float4 bv = *reinterpret_cast<const float4*>(pb + (size_t)(k0+brow)*PHW + h0 + bcol);
        bv.x -= bm; bv.y -= bm; bv.z -= bm; bv.w -= bm;
        __syncthreads();
        As[lc4+0][lr] = av.x; As[lc4+1][lr] = av.y; As[lc4+2][lr] = av.z; As[lc4+3][lr] = av.w;
        *reinterpret_cast<float4*>(&Bs[brow][bcol]) = bv;
        __syncthreads();
        #pragma unroll
        for (int kk = 0; kk < 16; ++kk) {
            float4 a4 = *reinterpret_cast<const float4*>(&As[kk][ty*4]);
            float4 b4 = *reinterpret_cast<const float4*>(&Bs[kk][tx*4]);
            float a[4] = {a4.x, a4.y, a4.z, a4.w};
            float bb[4] = {b4.x, b4.y, b4.z, b4.w};
            #pragma unroll
            for (int i = 0; i < 4; ++i)
                #pragma unroll
                for (int j = 0; j < 4; ++j)
                    acc[i][j] += a[i] * bb[j];
        }
    }
    __syncthreads();
    #pragma unroll
    for (int i = 0; i < 4; ++i)
        *reinterpret_cast<float4*>(&accS[ty*4+i][tx*4]) =
            make_float4(acc[i][0], acc[i][1], acc[i][2], acc[i][3]);
    __syncthreads();
    float mn = fdec(mm[0]);
    float mx = fdec(mm[1]);
    int lane_ch = t >> 5;           // 0..7
    int col4 = (t & 31) * 4;        // 4 output cols = 2 pooled pixels
    int pw2 = (t & 31) * 2;
    #pragma unroll
    for (int cc8 = 0; cc8 < 64; cc8 += 8) {
        int ch  = cc8 + lane_ch;
        int gch = c0 + ch;
        float me = mb[gch];
        float2 av = *reinterpret_cast<const float2*>(&accS[ch][pw2]);
        float t0 = fminf(fmaxf(av.x + me, mn), mx);
        float t1 = fminf(fmaxf(av.y + me, mn), mx);
        float2 pv = *reinterpret_cast<const float2*>(
            pb + (size_t)gch * PHW + h0 + pw2);
        size_t xbase = (((size_t)b * C_DIM + gch) * H_DIM + 2*ph) * W_DIM + col4;
        #pragma unroll
        for (int row = 0; row < 2; ++row) {
            float4 xv = *reinterpret_cast<const float4*>(x + xbase + row*W_DIM);
            float4 o;
            o.x = xv.x - pv.x + t0;
            o.y = xv.y - pv.x + t0;
            o.z = xv.z - pv.y + t1;
            o.w = xv.w - pv.y + t1;
            *reinterpret_cast<float4*>(out + xbase + row*W_DIM) = o;
        }
    }
}

extern "C" void kernel_launch(void* const* d_in, const int* in_sizes, int n_in,
                              void* d_out, int out_size, void* d_ws, size_t ws_size,
                              hipStream_t stream)
{
    const float* x   = (const float*)d_in[0];
    const float* eps = (const float*)d_in[1];
    float* out = (float*)d_out;
    float* w = (float*)d_ws;

    size_t o = 0;
    float* p    = w + o; o += (size_t)N_B * C_DIM * PHW;  // 8,388,608
    float* bufA = w + o; o += (size_t)N_B * CC;  // wms
    float* bufY = w + o; o += (size_t)N_B * CC;
    float* bufZ = w + o; o += (size_t)N_B * CC;
    float* bufY2= w + o; o += (size_t)N_B * CC;
    float* bufZ2= w + o; o += (size_t)N_B * CC;
    float* bufW = w + o; o += (size_t)N_B * CC;
    float* bufT = w + o; o += (size_t)N_B * CC;
    float* meanb= w + o; o += N_B * C_DIM;
    float* sqb  = w + o; o += N_B * C_DIM;
    float* cvec = w + o; o += N_B;
    float* scv  = w + o; o += N_B;
    float* tm   = w + o; o += N_B;
    float* ts   = w + o; o += N_B;
    unsigned int* mmx = (unsigned int*)(w + o); o += 2;

    // aliases (lifetime-disjoint)
    float* wms  = bufA;
    float* covp0 = bufY2, *covp1 = bufZ, *covp2 = bufZ2, *covp3 = bufT;
    float* invA11 = bufW;                             // after NS, bufW free
    float* T1     = bufW + (size_t)N_B * 128 * 128;
    float* Sm     = bufW + (size_t)N_B * 128 * 128 * 2;
    float* Minv   = bufY2;
    float* Rb     = bufZ2;
    float* Minv2  = bufY;
    float* Mm     = bufT;

    hipMemsetAsync(mmx,     0xFF, 4, stream);
    hipMemsetAsync(mmx + 1, 0x00, 4, stream);

    pool_kernel<<<N_B * C_DIM, 256, 0, stream>>>(x, p, meanb, sqb, mmx);
    cvec_kernel<<<N_B, 256, 0, stream>>>(meanb, sqb, cvec, scv);
    cov_part_kernel<<<dim3(4, 4, N_B*4), 256, 0, stream>>>(p, meanb, covp0, covp1, covp2, covp3);
    combine_kernel<<<2048, 256, 0, stream>>>(covp0, covp1, covp2, covp3, cvec, bufY, bufW);

    const long long S  = (long long)CC;
    const long long Sh = 128LL * 128LL;

    // ---- Newton-Schulz, 5 iterations. it1 simplified: Z1 = W0 (elementwise, done in combine) ----
    // it1: Y1 = Y0 @ W0
    gemm_kernel<<<dim3(4,4,N_B), 256, 0, stream>>>(bufY,256,S, bufW,256,S, bufY2,256,S,
                                                   nullptr,0,0, nullptr, 256, 1.0f, 0.0f, 0.0f);
    // it2: W=f(Z1=bufW, Y1=bufY2)->bufY ; Y2->bufZ ; Z2->bufZ2
    gemm_kernel<<<dim3(4,4,N_B), 256, 0, stream>>>(bufW,256,S, bufY2,256,S, bufY,256,S,
                                                   nullptr,0,0, nullptr, 256, -0.5f, 1.5f, 0.0f);
    ns_pair_kernel<<<dim3(4,4,2*N_B), 256, 0, stream>>>(bufY2, bufW, bufY, bufZ, bufZ2);
    // it3: W=f(Z2=bufZ2, Y2=bufZ)->bufY2 ; Y3->bufW ; Z3->bufY
    gemm_kernel<<<dim3(4,4,N_B), 256, 0, stream>>>(bufZ2,256,S, bufZ,256,S, bufY2,256,S,
                                                   nullptr,0,0, nullptr, 256, -0.5f, 1.5f, 0.0f);
    ns_pair_kernel<<<dim3(4,4,2*N_B), 256, 0, stream>>>(bufZ, bufZ2, bufY2, bufW, bufY);
    // it4: W=f(Z3=bufY, Y3=bufW)->bufZ ; Y4->bufZ2 ; Z4->bufY2
    gemm_kernel<<<dim3(4,4,N_B), 256, 0, stream>>>(bufY,256,S, bufW,256,S, bufZ,256,S,
                                                   nullptr,0,0, nullptr, 256, -0.5f, 1.5f, 0.0f);
    ns_pair_kernel<<<dim3(4,4,2*N_B), 256, 0, stream>>>(bufW, bufY, bufZ, bufZ2, bufY2);
    // it5: W=f(Z4=bufY2, Y4=bufZ2)->bufY ; Z5 = W@Z4 -> bufZ  (skip dead Y5)
    gemm_kernel<<<dim3(4,4,N_B), 256, 0, stream>>>(bufY2,256,S, bufZ2,256,S, bufY,256,S,
                                                   nullptr,0,0, nullptr, 256, -0.5f, 1.5f, 0.0f);
    gemm_kernel<<<dim3(4,4,N_B), 256, 0, stream>>>(bufY,256,S, bufY2,256,S, bufZ,256,S,
                                                   nullptr,0,0, nullptr, 256, 1.0f, 0.0f, 0.0f);
    // final Z (= wm * sqrt(c)) in bufZ; wm = scv[b]*bufZ (folded into consumers)

    tex_stats_kernel<<<N_B, 256, 0, stream>>>(bufZ, scv, tm, ts);
    assemble_kernel<<<2048, 256, 0, stream>>>(bufZ, scv, eps, tm, ts, wms);

    // ---- Schur-complement inverse of wms (2x2 blocks of 128) ----
    gj_inv128_kernel<<<N_B, 256, 0, stream>>>(wms, 256, S, invA11, 128, Sh);
    // T1 = invA11 @ A12
    gemm_kernel<<<dim3(2,2,N_B), 256, 0, stream>>>(invA11,128,Sh, wms+128,256,S, T1,128,Sh,
                                                   nullptr,0,0, nullptr, 128, 1.0f, 0.0f, 0.0f);
    // Sm = A22 - A21 @ T1
    gemm_kernel<<<dim3(2,2,N_B), 256, 0, stream>>>(wms+128*256,256,S, T1,128,Sh, Sm,128,Sh,
                                                   wms+128*256+128,256,S, nullptr, 128, -1.0f, 0.0f, 1.0f);
    // invS -> Minv22
    gj_inv128_kernel<<<N_B, 256, 0, stream>>>(Sm, 128, Sh, Minv+128*256+128, 256, S);
    // M12 = -T1 @ invS
    gemm_kernel<<<dim3(2,2,N_B), 256, 0, stream>>>(T1,128,Sh, Minv+128*256+128,256,S, Minv+128,256,S,
                                                   nullptr,0,0, nullptr, 128, -1.0f, 0.0f, 0.0f);
    // M21 = M12^T  (invS, invA11 symmetric)
    transpose128_kernel<<<dim3(8,8,N_B), 256, 0, stream>>>(Minv+128, Minv+128*256);
    // M11 = invA11 - T1 @ M21
    gemm_kernel<<<dim3(2,2,N_B), 256, 0, stream>>>(T1,128,Sh, Minv+128*256,256,S, Minv,256,S,
                                                   invA11,128,Sh, nullptr, 128, -1.0f, 0.0f, 1.0f);
    // ---- one Newton refinement: Minv2 = Minv (2I - wms Minv) ----
    gemm_kernel<<<dim3(4,4,N_B), 256, 0, stream>>>(wms,256,S, Minv,256,S, Rb,256,S,
                                                   nullptr,0,0, nullptr, 256, -1.0f, 2.0f, 0.0f);
    gemm_kernel<<<dim3(4,4,N_B), 256, 0, stream>>>(Minv,256,S, Rb,256,S, Minv2,256,S,
                                                   nullptr,0,0, nullptr, 256, 1.0f, 0.0f, 0.0f);
    // Mm = Minv2 @ wm = scv[b] * (Minv2 @ Zf)
    gemm_kernel<<<dim3(4,4,N_B), 256, 0, stream>>>(Minv2,256,S, bufZ,256,S, Mm,256,S,
                                                   nullptr,0,0, scv, 256, 1.0f, 0.0f, 0.0f);

    target_kernel<<<dim3(4, 64, N_B), 256, 0, stream>>>(Mm, p, meanb, x, mmx, out);

    (void)in_sizes; (void)n_in; (void)out_size; (void)ws_size;
}

// Round 5
// 989.152 us; speedup vs baseline: 1.6856x; 1.1750x over previous
//
#include <hip/hip_runtime.h>
#include <math.h>

#define N_B   8
#define C_DIM 256
#define H_DIM 128
#define W_DIM 128
#define HW    (H_DIM*W_DIM)   // 16384
#define PH    64
#define PW    64
#define PHW   (PH*PW)         // 4096
#define CC    (C_DIM*C_DIM)   // 65536
#define EPS_COV 1e-5f
#define COVSCALE (4.0f / 16383.0f)
#define NBGJ 16
#define PGLD 33

__device__ inline unsigned int fenc(float f) {
    unsigned int u = __float_as_uint(f);
    return (u & 0x80000000u) ? ~u : (u | 0x80000000u);
}
__device__ inline float fdec(unsigned int u) {
    return (u & 0x80000000u) ? __uint_as_float(u & 0x7fffffffu) : __uint_as_float(~u);
}

// ---------------- pool (2x2 mean) + per-(n,c) sum/sumsq + global min/max ----------------
__global__ void pool_kernel(const float* __restrict__ x, float* __restrict__ p,
                            float* __restrict__ mean, float* __restrict__ sqb,
                            unsigned int* __restrict__ mm)
{
    int nc = blockIdx.x;        // 0..2047
    int t  = threadIdx.x;       // 0..255
    const float* xp = x + (size_t)nc * HW;
    float* pp = p + (size_t)nc * PHW;
    float lsum = 0.f, lsq = 0.f, lmin = 1e30f, lmax = -1e30f;
    #pragma unroll
    for (int i = 0; i < PHW/256; ++i) {
        int pidx = i*256 + t;
        int ph = pidx >> 6, pw = pidx & 63;
        const float* r0 = xp + (size_t)(2*ph)*W_DIM + 2*pw;
        float2 a = *reinterpret_cast<const float2*>(r0);
        float2 b = *reinterpret_cast<const float2*>(r0 + W_DIM);
        float v = (a.x + a.y + b.x + b.y) * 0.25f;
        pp[pidx] = v;
        lsum += v;
        lsq  += v * v;
        lmin = fminf(lmin, v);
        lmax = fmaxf(lmax, v);
    }
    __shared__ float ssum[256], ssq[256], smin[256], smax[256];
    ssum[t] = lsum; ssq[t] = lsq; smin[t] = lmin; smax[t] = lmax;
    __syncthreads();
    for (int s = 128; s > 0; s >>= 1) {
        if (t < s) {
            ssum[t] += ssum[t+s];
            ssq[t]  += ssq[t+s];
            smin[t] = fminf(smin[t], smin[t+s]);
            smax[t] = fmaxf(smax[t], smax[t+s]);
        }
        __syncthreads();
    }
    if (t == 0) {
        mean[nc] = ssum[0] / (float)PHW;
        sqb[nc]  = ssq[0];
        atomicMin(&mm[0], fenc(smin[0]));
        atomicMax(&mm[1], fenc(smax[0]));
    }
}

// ---------------- cvec[b] = mean_c(diag cov) (incl eps); scv = 1/sqrt ----------------
__global__ void cvec_kernel(const float* __restrict__ mean, const float* __restrict__ sqb,
                            float* __restrict__ cvec, float* __restrict__ scv)
{
    int b = blockIdx.x, t = threadIdx.x;
    float m = mean[b*C_DIM + t];
    float s2 = sqb[b*C_DIM + t];
    float cv = COVSCALE * (s2 - (float)PHW * m * m) + EPS_COV;
    __shared__ float s[256];
    s[t] = cv; __syncthreads();
    for (int st = 128; st > 0; st >>= 1) {
        if (t < st) s[t] += s[t+st];
        __syncthreads();
    }
    if (t == 0) {
        float c = s[0] / 256.0f;
        cvec[b] = c;
        scv[b] = 1.0f / sqrtf(c);
    }
}

// ---------------- cov partial: raw pc@pc^T over a K-slice (symmetric blocks) ----------
__global__ void cov_part_kernel(const float* __restrict__ p, const float* __restrict__ mean,
                                float* __restrict__ c0p, float* __restrict__ c1p,
                                float* __restrict__ c2p, float* __restrict__ c3p)
{
    int bx = blockIdx.x, by = blockIdx.y;
    if (bx > by) return;                      // symmetry
    int bz = blockIdx.z;
    int b  = bz >> 2, ks = bz & 3;
    float* covp = (ks == 0) ? c0p : (ks == 1) ? c1p : (ks == 2) ? c2p : c3p;
    int c0 = bx * 64, d0 = by * 64;
    int t  = threadIdx.x;
    int tx = t & 15, ty = t >> 4;
    __shared__ float As[16][68];
    __shared__ float Bs[16][68];
    const float* pb = p + (size_t)b * C_DIM * PHW;
    const float* mb = mean + b * C_DIM;
    int lr  = t >> 2;
    int lc4 = (t & 3) * 4;
    float am = mb[c0 + lr];
    float bm = mb[d0 + lr];
    const float* aptr = pb + (size_t)(c0 + lr) * PHW + ks*1024 + lc4;
    const float* bptr = pb + (size_t)(d0 + lr) * PHW + ks*1024 + lc4;
    float acc[4][4] = {};
    for (int k0 = 0; k0 < 1024; k0 += 16) {
        float4 av = *reinterpret_cast<const float4*>(aptr + k0);
        float4 bv = *reinterpret_cast<const float4*>(bptr + k0);
        __syncthreads();
        As[lc4+0][lr] = av.x - am; As[lc4+1][lr] = av.y - am;
        As[lc4+2][lr] = av.z - am; As[lc4+3][lr] = av.w - am;
        Bs[lc4+0][lr] = bv.x - bm; Bs[lc4+1][lr] = bv.y - bm;
        Bs[lc4+2][lr] = bv.z - bm; Bs[lc4+3][lr] = bv.w - bm;
        __syncthreads();
        #pragma unroll
        for (int kk = 0; kk < 16; ++kk) {
            float4 a4 = *reinterpret_cast<const float4*>(&As[kk][ty*4]);
            float4 b4 = *reinterpret_cast<const float4*>(&Bs[kk][tx*4]);
            float a[4] = {a4.x, a4.y, a4.z, a4.w};
            float bb[4] = {b4.x, b4.y, b4.z, b4.w};
            #pragma unroll
            for (int i = 0; i < 4; ++i)
                #pragma unroll
                for (int j = 0; j < 4; ++j)
                    acc[i][j] += a[i] * bb[j];
        }
    }
    float* cb = covp + (size_t)b * CC;
    #pragma unroll
    for (int i = 0; i < 4; ++i) {
        int ci = c0 + ty*4 + i;
        #pragma unroll
        for (int j = 0; j < 4; ++j) {
            int dj = d0 + tx*4 + j;
            cb[(size_t)ci * C_DIM + dj] = acc[i][j];
            cb[(size_t)dj * C_DIM + ci] = acc[i][j];
        }
    }
}

// ---------------- combine partials -> Y0 = cov/c, W0 = 1.5I - 0.5 Y0 ----------------
__global__ void combine_kernel(const float* __restrict__ c0p, const float* __restrict__ c1p,
                               const float* __restrict__ c2p, const float* __restrict__ c3p,
                               const float* __restrict__ cvec,
                               float* __restrict__ Y, float* __restrict__ W0)
{
    size_t idx = (size_t)blockIdx.x * 256 + threadIdx.x;
    int b  = (int)(idx >> 16);
    int ij = (int)(idx & 65535);
    int diag = ((ij >> 8) == (ij & 255));
    float s = (c0p[idx] + c1p[idx] + c2p[idx] + c3p[idx]) * COVSCALE;
    float covv = s + (diag ? EPS_COV : 0.0f);
    float y = covv * (1.0f / cvec[b]);
    Y[idx] = y;
    W0[idx] = (diag ? 1.5f : 0.0f) - 0.5f * y;
}

// ---------------- shared 64x64-tile fp32 GEMM core ----------------
__device__ inline void tile64(const float* __restrict__ Ab, int lda,
                              const float* __restrict__ Bb, int ldb,
                              int n, int r0, int c0, int t,
                              float (&As)[16][68], float (&Bs)[16][68],
                              float (&acc)[4][4])
{
    int tx = t & 15, ty = t >> 4;
    int lr = t >> 2, lc4 = (t & 3) * 4;
    int brow = t >> 4, bcol = (t & 15) * 4;
    for (int k0 = 0; k0 < n; k0 += 16) {
        float4 av = *reinterpret_cast<const float4*>(Ab + (size_t)(r0+lr)*lda + k0 + lc4);
        float4 bv = *reinterpret_cast<const float4*>(Bb + (size_t)(k0+brow)*ldb + c0 + bcol);
        __syncthreads();
        As[lc4+0][lr] = av.x; As[lc4+1][lr] = av.y; As[lc4+2][lr] = av.z; As[lc4+3][lr] = av.w;
        *reinterpret_cast<float4*>(&Bs[brow][bcol]) = bv;
        __syncthreads();
        #pragma unroll
        for (int kk = 0; kk < 16; ++kk) {
            float4 a4 = *reinterpret_cast<const float4*>(&As[kk][ty*4]);
            float4 b4 = *reinterpret_cast<const float4*>(&Bs[kk][tx*4]);
            float a[4] = {a4.x, a4.y, a4.z, a4.w};
            float bb[4] = {b4.x, b4.y, b4.z, b4.w};
            #pragma unroll
            for (int i = 0; i < 4; ++i)
                #pragma unroll
                for (int j = 0; j < 4; ++j)
                    acc[i][j] += a[i] * bb[j];
        }
    }
}

// --------- generic batched n x n GEMM: C = alpha*alphav[b]*A@B + beta*I + gamma*Cin ---------
__global__ void gemm_kernel(const float* __restrict__ A, int lda, long long sA,
                            const float* __restrict__ B, int ldb, long long sB,
                            float* __restrict__ C, int ldc, long long sC,
                            const float* __restrict__ Cin, int ldcin, long long sCin,
                            const float* __restrict__ alphav,
                            int n, float alpha, float beta, float gamma)
{
    int b  = blockIdx.z;
    int r0 = blockIdx.x * 64, c0 = blockIdx.y * 64;
    int t  = threadIdx.x;
    int tx = t & 15, ty = t >> 4;
    __shared__ float As[16][68];
    __shared__ float Bs[16][68];
    float acc[4][4] = {};
    tile64(A + (size_t)b*sA, lda, B + (size_t)b*sB, ldb, n, r0, c0, t, As, Bs, acc);
    float al = alpha * (alphav ? alphav[b] : 1.0f);
    float* Cb = C + (size_t)b * sC;
    #pragma unroll
    for (int i = 0; i < 4; ++i) {
        int r = r0 + ty*4 + i;
        #pragma unroll
        for (int j = 0; j < 4; ++j) {
            int c = c0 + tx*4 + j;
            float v = al * acc[i][j];
            if (beta != 0.0f && r == c) v += beta;
            if (gamma != 0.0f) v += gamma * Cin[(size_t)b*sCin + (size_t)r*ldcin + c];
            Cb[(size_t)r*ldc + c] = v;
        }
    }
}

// ---------------- NS pair update: Yn = Y@W, Zn = W@Z in one launch ----------------
__global__ void ns_pair_kernel(const float* __restrict__ Y, const float* __restrict__ Z,
                               const float* __restrict__ W,
                               float* __restrict__ Yn, float* __restrict__ Zn)
{
    int bz = blockIdx.z;
    int b = bz >> 1, which = bz & 1;
    const float* A = which ? W + (size_t)b*CC : Y + (size_t)b*CC;
    const float* B = which ? Z + (size_t)b*CC : W + (size_t)b*CC;
    float*       C = which ? Zn + (size_t)b*CC : Yn + (size_t)b*CC;
    int r0 = blockIdx.x * 64, c0 = blockIdx.y * 64;
    int t  = threadIdx.x;
    int tx = t & 15, ty = t >> 4;
    __shared__ float As[16][68];
    __shared__ float Bs[16][68];
    float acc[4][4] = {};
    tile64(A, 256, B, 256, 256, r0, c0, t, As, Bs, acc);
    #pragma unroll
    for (int i = 0; i < 4; ++i)
        #pragma unroll
        for (int j = 0; j < 4; ++j)
            C[(size_t)(r0+ty*4+i)*256 + c0+tx*4+j] = acc[i][j];
}

// ------- strict-lower-triangle partial sums of RAW Z (scaling folded in later) -------
__global__ void tex_partial_kernel(const float* __restrict__ Zf,
                                   float* __restrict__ tsum, float* __restrict__ tsq)
{
    int bx = blockIdx.x;           // 0..255
    int b = bx >> 5, chunk = bx & 31;
    const float* w = Zf + (size_t)b * CC;
    int t = threadIdx.x;
    int base = chunk * 2048;
    float sum = 0.f, sq = 0.f;
    #pragma unroll
    for (int k = 0; k < 8; ++k) {
        int flat = base + k*256 + t;
        int i = flat >> 8, j = flat & 255;
        if (i > j) {
            float v = w[flat];
            sum += v; sq += v * v;
        }
    }
    __shared__ float s1[256], s2[256];
    s1[t] = sum; s2[t] = sq;
    __syncthreads();
    for (int st = 128; st > 0; st >>= 1) {
        if (t < st) { s1[t] += s1[t+st]; s2[t] += s2[t+st]; }
        __syncthreads();
    }
    if (t == 0) {
        atomicAdd(&tsum[b], s1[0]);
        atomicAdd(&tsq[b],  s2[0]);
    }
}

// ------- assemble wm_s (diag from wm = scv*Z); finalize stats inline -------
__global__ void assemble_kernel(const float* __restrict__ Zf, const float* __restrict__ scv,
                                const float* __restrict__ eps,
                                const float* __restrict__ tsum, const float* __restrict__ tsq,
                                float* __restrict__ wms)
{
    size_t idx = (size_t)blockIdx.x * 256 + threadIdx.x;
    int b  = (int)(idx >> 16);
    int ij = (int)(idx & 65535);
    int i = ij >> 8, j = ij & 255;
    float s = scv[b];
    float v;
    if (i == j) {
        v = Zf[idx] * s;
    } else {
        float sum = tsum[b] * s;
        float sq  = tsq[b] * s * s;
        float m = sum / 32640.0f;
        float var = (sq - 2.0f*m*sum + m*m*65536.0f) / 32640.0f;
        float sd = sqrtf(fmaxf(var, 0.0f));
        int lo = min(i, j), hi = max(i, j);
        v = m + 10.0f * sd * eps[(size_t)b*CC + (size_t)lo*256 + hi];
    }
    wms[idx] = v;
}

// ---- 128x128 blocked Gauss-Jordan inverse, virtual pivoting, registers-resident ----
// PG fuses panel (cols 0..15) and composed operator G (cols 16..31); G cols
// zero-initialized per panel so every row update is a full-width unrolled
// 32-FMA with all LDS loads issued in parallel (fixes the rolled-loop latency
// serialization measured in r4: 4400 cyc/step).
__global__ __launch_bounds__(256, 1)
void gj_inv128_kernel(const float* __restrict__ Ain, int lda, long long sA,
                      float* __restrict__ Out, int ldo, long long sO)
{
    __shared__ float PG[2][128][PGLD];
    __shared__ float Rs[NBGJ][256];
    __shared__ int   pivots[NBGJ];
    __shared__ int   rowdest[128];
    __shared__ int   used[128];
    __shared__ float sh_rp;
    __shared__ int   sh_p;

    int b = blockIdx.x;
    int t = threadIdx.x;          // 0..255
    int q = t & 15;               // col ownership: cols {q, q+16, ..., q+240}
    int rg = t >> 4;              // rows rg*8 .. rg*8+7
    const float* Ab = Ain + (size_t)b * sA;

    float Areg[8][16];
    #pragma unroll
    for (int rr = 0; rr < 8; ++rr) {
        int r = rg*8 + rr;
        #pragma unroll
        for (int cc = 0; cc < 16; ++cc) {
            int c = q + cc*16;
            Areg[rr][cc] = (c < 128) ? Ab[(size_t)r*lda + c]
                                     : ((c - 128 == r) ? 1.0f : 0.0f);
        }
    }
    if (t < 128) used[t] = 0;
    __syncthreads();

    for (int pb = 0; pb < 8; ++pb) {
        // dump panel cols into PG[0][:, 0..15], zero G cols 16..31
        #pragma unroll
        for (int rr = 0; rr < 8; ++rr) {
            float val = 0.f;
            #pragma unroll
            for (int cc = 0; cc < 16; ++cc)
                if (cc == pb) val = Areg[rr][cc];
            PG[0][rg*8 + rr][q] = val;
            PG[0][rg*8 + rr][16 + q] = 0.f;
        }
        __syncthreads();

        #pragma unroll
        for (int j = 0; j < NBGJ; ++j) {
            const int cur = j & 1;
            if (t < 64) {
                float v1 = used[t]    ? -1.f : fabsf(PG[cur][t][j]);
                float v2 = used[t+64] ? -1.f : fabsf(PG[cur][t+64][j]);
                int i1 = t;
                if (v2 > v1) { v1 = v2; i1 = t + 64; }
                #pragma unroll
                for (int m = 32; m; m >>= 1) {
                    float ov = __shfl_xor(v1, m);
                    int   oi = __shfl_xor(i1, m);
                    if (ov > v1) { v1 = ov; i1 = oi; }
                }
                if (t == 0) {
                    sh_p = i1;
                    sh_rp = 1.0f / PG[cur][i1][j];
                    pivots[j] = i1;
                    rowdest[i1] = pb*NBGJ + j;
                    used[i1] = 1;
                }
            }
            __syncthreads();
            if (t < 128) {
                int p = sh_p; float rp = sh_rp;
                float f = PG[cur][t][j];
                float v = (t == p) ? (rp - 1.0f) : (-f * rp);
                #pragma unroll
                for (int jj = 0; jj < 32; ++jj) {
                    float nv = fmaf(v, PG[cur][p][jj], PG[cur][t][jj]);
                    PG[cur^1][t][jj] = (jj == 16 + j) ? v : nv;
                }
            }
            __syncthreads();
        }
        // after 16 steps (j=15, cur=1 wrote cur^1=0): final G in PG[0][:, 16..31]

        // gather OLD pivot rows (pre-panel register values) into Rs
        for (int j = 0; j < NBGJ; ++j) {
            int p = pivots[j];
            if ((p >> 3) == rg) {
                #pragma unroll
                for (int rr = 0; rr < 8; ++rr)
                    if ((p & 7) == rr) {
                        #pragma unroll
                        for (int cc = 0; cc < 16; ++cc)
                            Rs[j][q + cc*16] = Areg[rr][cc];
                    }
            }
        }
        __syncthreads();

        // trailing rank-16 update: A[r,c] += sum_j G[r,j] * R[j,c]
        #pragma unroll
        for (int j = 0; j < NBGJ; ++j) {
            float rv[16];
            #pragma unroll
            for (int cc = 0; cc < 16; ++cc) rv[cc] = Rs[j][q + cc*16];
            #pragma unroll
            for (int rr = 0; rr < 8; ++rr) {
                float g = PG[0][rg*8 + rr][16 + j];
                #pragma unroll
                for (int cc = 0; cc < 16; ++cc)
                    Areg[rr][cc] = fmaf(g, rv[cc], Areg[rr][cc]);
            }
        }
        __syncthreads();
    }

    float* Ob = Out + (size_t)b * sO;
    #pragma unroll
    for (int rr = 0; rr < 8; ++rr) {
        int r = rg*8 + rr;
        int dest = rowdest[r];
        #pragma unroll
        for (int cc = 8; cc < 16; ++cc) {
            int c = q + cc*16;            // 128..255
            Ob[(size_t)dest*ldo + (c - 128)] = Areg[rr][cc];
        }
    }
}

// ---------------- M21 = M12^T (batched 128x128 transpose, In/Out ld=256) ----------------
__global__ void transpose128_kernel(const float* __restrict__ In, float* __restrict__ Outp)
{
    __shared__ float tile[16][17];
    int b = blockIdx.z;
    int r0 = blockIdx.y * 16, c0 = blockIdx.x * 16;
    int t = threadIdx.x;
    int tx = t & 15, ty = t >> 4;
    tile[ty][tx] = In[(size_t)b*CC + (size_t)(r0+ty)*256 + c0+tx];
    __syncthreads();
    Outp[(size_t)b*CC + (size_t)(c0+ty)*256 + r0+tx] = tile[tx][ty];
}

// ------- fused: target-pool GEMM (M @ (p-mean)) + upsample + clip + HH + write out -------
__global__ void target_kernel(const float* __restrict__ M, const float* __restrict__ p,
                              const float* __restrict__ mean, const float* __restrict__ x,
                              const unsigned int* __restrict__ mm, float* __restrict__ out)
{
    int b  = blockIdx.z;
    int c0 = blockIdx.x * 64;     // channel block
    int ph = blockIdx.y;          // pooled row
    int h0 = ph * 64;
    int t  = threadIdx.x;
    int tx = t & 15, ty = t >> 4;
    __shared__ float As[16][68];
    __shared__ float Bs[16][68];
    __shared__ float accS[64][66];
    const float* Mb = M + (size_t)b * CC;
    const float* pb = p + (size_t)b * C_DIM * PHW;
    const float* mb = mean + b * C_DIM;
    int lr   = t >> 2;
    int lc4  = (t & 3) * 4;
    int brow = t >> 4;
    int bcol = (t & 15) * 4;
    float acc[4][4] = {};
    for (int k0 = 0; k0 < C_DIM; k0 += 16) {
        float4 av = *reinterpret_cast<const float4*>(Mb + (size_t)(c0+lr)*C_DIM + k0 + lc4);
        float  bm = mb[k0 + brow];
        float4 bv = *reinterpret_cast<const float4*>(pb + (size_t)(k0+brow)*PHW + h0 + bcol);
        bv.x -= bm; bv.y -= bm; bv.z -= bm; bv.w -= bm;
        __syncthreads();
        As[lc4+0][lr] = av.x; As[lc4+1][lr] = av.y; As[lc4+2][lr] = av.z; As[lc4+3][lr] = av.w;
        *reinterpret_cast<float4*>(&Bs[brow][bcol]) = bv;
        __syncthreads();
        #pragma unroll
        for (int kk = 0; kk < 16; ++kk) {
            float4 a4 = *reinterpret_cast<const float4*>(&As[kk][ty*4]);
            float4 b4 = *reinterpret_cast<const float4*>(&Bs[kk][tx*4]);
            float a[4] = {a4.x, a4.y, a4.z, a4.w};
            float bb[4] = {b4.x, b4.y, b4.z, b4.w};
            #pragma unroll
            for (int i = 0; i < 4; ++i)
                #pragma unroll
                for (int j = 0; j < 4; ++j)
                    acc[i][j] += a[i] * bb[j];
        }
    }
    __syncthreads();
    #pragma unroll
    for (int i = 0; i < 4; ++i)
        *reinterpret_cast<float4*>(&accS[ty*4+i][tx*4]) =
            make_float4(acc[i][0], acc[i][1], acc[i][2], acc[i][3]);
    __syncthreads();
    float mn = fdec(mm[0]);
    float mx = fdec(mm[1]);
    int lane_ch = t >> 5;           // 0..7
    int col4 = (t & 31) * 4;        // 4 output cols = 2 pooled pixels
    int pw2 = (t & 31) * 2;
    #pragma unroll
    for (int cc8 = 0; cc8 < 64; cc8 += 8) {
        int ch  = cc8 + lane_ch;
        int gch = c0 + ch;
        float me = mb[gch];
        float2 av = *reinterpret_cast<const float2*>(&accS[ch][pw2]);
        float t0 = fminf(fmaxf(av.x + me, mn), mx);
        float t1 = fminf(fmaxf(av.y + me, mn), mx);
        float2 pv = *reinterpret_cast<const float2*>(
            pb + (size_t)gch * PHW + h0 + pw2);
        size_t xbase = (((size_t)b * C_DIM + gch) * H_DIM + 2*ph) * W_DIM + col4;
        #pragma unroll
        for (int row = 0; row < 2; ++row) {
            float4 xv = *reinterpret_cast<const float4*>(x + xbase + row*W_DIM);
            float4 o;
            o.x = xv.x - pv.x + t0;
            o.y = xv.y - pv.x + t0;
            o.z = xv.z - pv.y + t1;
            o.w = xv.w - pv.y + t1;
            *reinterpret_cast<float4*>(out + xbase + row*W_DIM) = o;
        }
    }
}

extern "C" void kernel_launch(void* const* d_in, const int* in_sizes, int n_in,
                              void* d_out, int out_size, void* d_ws, size_t ws_size,
                              hipStream_t stream)
{
    const float* x   = (const float*)d_in[0];
    const float* eps = (const float*)d_in[1];
    float* out = (float*)d_out;
    float* w = (float*)d_ws;

    size_t o = 0;
    float* p    = w + o; o += (size_t)N_B * C_DIM * PHW;  // 8,388,608
    float* bufA = w + o; o += (size_t)N_B * CC;  // wms
    float* bufY = w + o; o += (size_t)N_B * CC;
    float* bufZ = w + o; o += (size_t)N_B * CC;
    float* bufY2= w + o; o += (size_t)N_B * CC;
    float* bufZ2= w + o; o += (size_t)N_B * CC;
    float* bufW = w + o; o += (size_t)N_B * CC;
    float* bufT = w + o; o += (size_t)N_B * CC;
    float* meanb= w + o; o += N_B * C_DIM;
    float* sqb  = w + o; o += N_B * C_DIM;
    float* cvec = w + o; o += N_B;
    float* scv  = w + o; o += N_B;
    float* tsum = w + o; o += N_B;
    float* tsq  = w + o; o += N_B;
    unsigned int* mmx = (unsigned int*)(w + o); o += 2;

    // aliases (lifetime-disjoint)
    float* wms  = bufA;
    float* covp0 = bufY2, *covp1 = bufZ, *covp2 = bufZ2, *covp3 = bufT;
    float* invA11 = bufW;
    float* T1     = bufW + (size_t)N_B * 128 * 128;
    float* Sm     = bufW + (size_t)N_B * 128 * 128 * 2;
    float* Minv   = bufY2;
    float* Rb     = bufZ;
    float* Minv2  = bufY;
    float* Mm     = bufT;

    hipMemsetAsync(mmx,     0xFF, 4, stream);
    hipMemsetAsync(mmx + 1, 0x00, 4, stream);
    hipMemsetAsync(tsum, 0, 2 * N_B * sizeof(float), stream);   // tsum+tsq

    pool_kernel<<<N_B * C_DIM, 256, 0, stream>>>(x, p, meanb, sqb, mmx);
    cvec_kernel<<<N_B, 256, 0, stream>>>(meanb, sqb, cvec, scv);
    cov_part_kernel<<<dim3(4, 4, N_B*4), 256, 0, stream>>>(p, meanb, covp0, covp1, covp2, covp3);
    combine_kernel<<<2048, 256, 0, stream>>>(covp0, covp1, covp2, covp3, cvec, bufY, bufW);

    const long long S  = (long long)CC;
    const long long Sh = 128LL * 128LL;

    // ---- Newton-Schulz, 4 iterations (e: .5625 -> .193 -> .030 -> 6.7e-4 -> 3.3e-7) ----
    // it1 (Z1 = W0 elementwise, from combine): Y1 = Y0@W0 -> bufY2
    gemm_kernel<<<dim3(4,4,N_B), 256, 0, stream>>>(bufY,256,S, bufW,256,S, bufY2,256,S,
                                                   nullptr,0,0, nullptr, 256, 1.0f, 0.0f, 0.0f);
    // it2: W2 = 1.5I - 0.5*Z1@Y1 -> bufY ; pair: Y2=Y1@W2 -> bufZ, Z2=W2@Z1 -> bufZ2
    gemm_kernel<<<dim3(4,4,N_B), 256, 0, stream>>>(bufW,256,S, bufY2,256,S, bufY,256,S,
                                                   nullptr,0,0, nullptr, 256, -0.5f, 1.5f, 0.0f);
    ns_pair_kernel<<<dim3(4,4,2*N_B), 256, 0, stream>>>(bufY2, bufW, bufY, bufZ, bufZ2);
    // it3: W3 = f(Z2@Y2) -> bufY2 ; pair: Y3=Y2@W3 -> bufW, Z3=W3@Z2 -> bufY
    gemm_kernel<<<dim3(4,4,N_B), 256, 0, stream>>>(bufZ2,256,S, bufZ,256,S, bufY2,256,S,
                                                   nullptr,0,0, nullptr, 256, -0.5f, 1.5f, 0.0f);
    ns_pair_kernel<<<dim3(4,4,2*N_B), 256, 0, stream>>>(bufZ, bufZ2, bufY2, bufW, bufY);
    // it4: W4 = f(Z3@Y3) -> bufZ ; Z4 = W4@Z3 -> bufZ2 (skip dead Y4)
    gemm_kernel<<<dim3(4,4,N_B), 256, 0, stream>>>(bufY,256,S, bufW,256,S, bufZ,256,S,
                                                   nullptr,0,0, nullptr, 256, -0.5f, 1.5f, 0.0f);
    gemm_kernel<<<dim3(4,4,N_B), 256, 0, stream>>>(bufZ,256,S, bufY,256,S, bufZ2,256,S,
                                                   nullptr,0,0, nullptr, 256, 1.0f, 0.0f, 0.0f);
    // final Z4 (= wm * sqrt(c)) in bufZ2; wm = scv[b]*Z4 folded into consumers

    tex_partial_kernel<<<256, 256, 0, stream>>>(bufZ2, tsum, tsq);
    assemble_kernel<<<2048, 256, 0, stream>>>(bufZ2, scv, eps, tsum, tsq, wms);

    // ---- Schur-complement inverse of wms (2x2 blocks of 128) ----
    gj_inv128_kernel<<<N_B, 256, 0, stream>>>(wms, 256, S, invA11, 128, Sh);
    gemm_kernel<<<dim3(2,2,N_B), 256, 0, stream>>>(invA11,128,Sh, wms+128,256,S, T1,128,Sh,
                                                   nullptr,0,0, nullptr, 128, 1.0f, 0.0f, 0.0f);
    gemm_kernel<<<dim3(2,2,N_B), 256, 0, stream>>>(wms+128*256,256,S, T1,128,Sh, Sm,128,Sh,
                                                   wms+128*256+128,256,S, nullptr, 128, -1.0f, 0.0f, 1.0f);
    gj_inv128_kernel<<<N_B, 256, 0, stream>>>(Sm, 128, Sh, Minv+128*256+128, 256, S);
    gemm_kernel<<<dim3(2,2,N_B), 256, 0, stream>>>(T1,128,Sh, Minv+128*256+128,256,S, Minv+128,256,S,
                                                   nullptr,0,0, nullptr, 128, -1.0f, 0.0f, 0.0f);
    transpose128_kernel<<<dim3(8,8,N_B), 256, 0, stream>>>(Minv+128, Minv+128*256);
    gemm_kernel<<<dim3(2,2,N_B), 256, 0, stream>>>(T1,128,Sh, Minv+128*256,256,S, Minv,256,S,
                                                   invA11,128,Sh, nullptr, 128, -1.0f, 0.0f, 1.0f);
    // ---- one Newton refinement: Minv2 = Minv (2I - wms Minv) ----
    gemm_kernel<<<dim3(4,4,N_B), 256, 0, stream>>>(wms,256,S, Minv,256,S, Rb,256,S,
                                                   nullptr,0,0, nullptr, 256, -1.0f, 2.0f, 0.0f);
    gemm_kernel<<<dim3(4,4,N_B), 256, 0, stream>>>(Minv,256,S, Rb,256,S, Minv2,256,S,
                                                   nullptr,0,0, nullptr, 256, 1.0f, 0.0f, 0.0f);
    // Mm = Minv2 @ wm = scv[b] * (Minv2 @ Z4)
    gemm_kernel<<<dim3(4,4,N_B), 256, 0, stream>>>(Minv2,256,S, bufZ2,256,S, Mm,256,S,
                                                   nullptr,0,0, scv, 256, 1.0f, 0.0f, 0.0f);

    target_kernel<<<dim3(4, 64, N_B), 256, 0, stream>>>(Mm, p, meanb, x, mmx, out);

    (void)in_sizes; (void)n_in; (void)out_size; (void)ws_size;
}

// Round 6
// 826.839 us; speedup vs baseline: 2.0165x; 1.1963x over previous
//
#include <hip/hip_runtime.h>
#include <math.h>

#define N_B   8
#define C_DIM 256
#define H_DIM 128
#define W_DIM 128
#define HW    (H_DIM*W_DIM)   // 16384
#define PH    64
#define PW    64
#define PHW   (PH*PW)         // 4096
#define CC    (C_DIM*C_DIM)   // 65536
#define EPS_COV 1e-5f
#define COVSCALE (4.0f / 16383.0f)
#define NBGJ 16

__device__ inline unsigned int fenc(float f) {
    unsigned int u = __float_as_uint(f);
    return (u & 0x80000000u) ? ~u : (u | 0x80000000u);
}
__device__ inline float fdec(unsigned int u) {
    return (u & 0x80000000u) ? __uint_as_float(u & 0x7fffffffu) : __uint_as_float(~u);
}

// ---------------- pool (2x2 mean) + per-(n,c) sum/sumsq + global min/max ----------------
__global__ void pool_kernel(const float* __restrict__ x, float* __restrict__ p,
                            float* __restrict__ mean, float* __restrict__ sqb,
                            unsigned int* __restrict__ mm)
{
    int nc = blockIdx.x;        // 0..2047
    int t  = threadIdx.x;       // 0..255
    const float* xp = x + (size_t)nc * HW;
    float* pp = p + (size_t)nc * PHW;
    float lsum = 0.f, lsq = 0.f, lmin = 1e30f, lmax = -1e30f;
    #pragma unroll
    for (int i = 0; i < PHW/256; ++i) {
        int pidx = i*256 + t;
        int ph = pidx >> 6, pw = pidx & 63;
        const float* r0 = xp + (size_t)(2*ph)*W_DIM + 2*pw;
        float2 a = *reinterpret_cast<const float2*>(r0);
        float2 b = *reinterpret_cast<const float2*>(r0 + W_DIM);
        float v = (a.x + a.y + b.x + b.y) * 0.25f;
        pp[pidx] = v;
        lsum += v;
        lsq  += v * v;
        lmin = fminf(lmin, v);
        lmax = fmaxf(lmax, v);
    }
    __shared__ float ssum[256], ssq[256], smin[256], smax[256];
    ssum[t] = lsum; ssq[t] = lsq; smin[t] = lmin; smax[t] = lmax;
    __syncthreads();
    for (int s = 128; s > 0; s >>= 1) {
        if (t < s) {
            ssum[t] += ssum[t+s];
            ssq[t]  += ssq[t+s];
            smin[t] = fminf(smin[t], smin[t+s]);
            smax[t] = fmaxf(smax[t], smax[t+s]);
        }
        __syncthreads();
    }
    if (t == 0) {
        mean[nc] = ssum[0] / (float)PHW;
        sqb[nc]  = ssq[0];
        atomicMin(&mm[0], fenc(smin[0]));
        atomicMax(&mm[1], fenc(smax[0]));
    }
}

// ---------------- cvec[b] = mean_c(diag cov) (incl eps); scv = 1/sqrt ----------------
__global__ void cvec_kernel(const float* __restrict__ mean, const float* __restrict__ sqb,
                            float* __restrict__ cvec, float* __restrict__ scv)
{
    int b = blockIdx.x, t = threadIdx.x;
    float m = mean[b*C_DIM + t];
    float s2 = sqb[b*C_DIM + t];
    float cv = COVSCALE * (s2 - (float)PHW * m * m) + EPS_COV;
    __shared__ float s[256];
    s[t] = cv; __syncthreads();
    for (int st = 128; st > 0; st >>= 1) {
        if (t < st) s[t] += s[t+st];
        __syncthreads();
    }
    if (t == 0) {
        float c = s[0] / 256.0f;
        cvec[b] = c;
        scv[b] = 1.0f / sqrtf(c);
    }
}

// ---------------- cov partial: raw pc@pc^T over a K-slice (symmetric blocks) ----------
__global__ void cov_part_kernel(const float* __restrict__ p, const float* __restrict__ mean,
                                float* __restrict__ c0p, float* __restrict__ c1p,
                                float* __restrict__ c2p, float* __restrict__ c3p)
{
    int bx = blockIdx.x, by = blockIdx.y;
    if (bx > by) return;                      // symmetry
    int bz = blockIdx.z;
    int b  = bz >> 2, ks = bz & 3;
    float* covp = (ks == 0) ? c0p : (ks == 1) ? c1p : (ks == 2) ? c2p : c3p;
    int c0 = bx * 64, d0 = by * 64;
    int t  = threadIdx.x;
    int tx = t & 15, ty = t >> 4;
    __shared__ float As[16][68];
    __shared__ float Bs[16][68];
    const float* pb = p + (size_t)b * C_DIM * PHW;
    const float* mb = mean + b * C_DIM;
    int lr  = t >> 2;
    int lc4 = (t & 3) * 4;
    float am = mb[c0 + lr];
    float bm = mb[d0 + lr];
    const float* aptr = pb + (size_t)(c0 + lr) * PHW + ks*1024 + lc4;
    const float* bptr = pb + (size_t)(d0 + lr) * PHW + ks*1024 + lc4;
    float acc[4][4] = {};
    for (int k0 = 0; k0 < 1024; k0 += 16) {
        float4 av = *reinterpret_cast<const float4*>(aptr + k0);
        float4 bv = *reinterpret_cast<const float4*>(bptr + k0);
        __syncthreads();
        As[lc4+0][lr] = av.x - am; As[lc4+1][lr] = av.y - am;
        As[lc4+2][lr] = av.z - am; As[lc4+3][lr] = av.w - am;
        Bs[lc4+0][lr] = bv.x - bm; Bs[lc4+1][lr] = bv.y - bm;
        Bs[lc4+2][lr] = bv.z - bm; Bs[lc4+3][lr] = bv.w - bm;
        __syncthreads();
        #pragma unroll
        for (int kk = 0; kk < 16; ++kk) {
            float4 a4 = *reinterpret_cast<const float4*>(&As[kk][ty*4]);
            float4 b4 = *reinterpret_cast<const float4*>(&Bs[kk][tx*4]);
            float a[4] = {a4.x, a4.y, a4.z, a4.w};
            float bb[4] = {b4.x, b4.y, b4.z, b4.w};
            #pragma unroll
            for (int i = 0; i < 4; ++i)
                #pragma unroll
                for (int j = 0; j < 4; ++j)
                    acc[i][j] += a[i] * bb[j];
        }
    }
    float* cb = covp + (size_t)b * CC;
    #pragma unroll
    for (int i = 0; i < 4; ++i) {
        int ci = c0 + ty*4 + i;
        #pragma unroll
        for (int j = 0; j < 4; ++j) {
            int dj = d0 + tx*4 + j;
            cb[(size_t)ci * C_DIM + dj] = acc[i][j];
            cb[(size_t)dj * C_DIM + ci] = acc[i][j];
        }
    }
}

// ---------------- combine partials -> Y0 = cov/c, W0 = 1.5I - 0.5 Y0 ----------------
__global__ void combine_kernel(const float* __restrict__ c0p, const float* __restrict__ c1p,
                               const float* __restrict__ c2p, const float* __restrict__ c3p,
                               const float* __restrict__ cvec,
                               float* __restrict__ Y, float* __restrict__ W0)
{
    size_t idx = (size_t)blockIdx.x * 256 + threadIdx.x;
    int b  = (int)(idx >> 16);
    int ij = (int)(idx & 65535);
    int diag = ((ij >> 8) == (ij & 255));
    float s = (c0p[idx] + c1p[idx] + c2p[idx] + c3p[idx]) * COVSCALE;
    float covv = s + (diag ? EPS_COV : 0.0f);
    float y = covv * (1.0f / cvec[b]);
    Y[idx] = y;
    W0[idx] = (diag ? 1.5f : 0.0f) - 0.5f * y;
}

// ---------------- shared 64x64-tile fp32 GEMM core ----------------
__device__ inline void tile64(const float* __restrict__ Ab, int lda,
                              const float* __restrict__ Bb, int ldb,
                              int n, int r0, int c0, int t,
                              float (&As)[16][68], float (&Bs)[16][68],
                              float (&acc)[4][4])
{
    int tx = t & 15, ty = t >> 4;
    int lr = t >> 2, lc4 = (t & 3) * 4;
    int brow = t >> 4, bcol = (t & 15) * 4;
    for (int k0 = 0; k0 < n; k0 += 16) {
        float4 av = *reinterpret_cast<const float4*>(Ab + (size_t)(r0+lr)*lda + k0 + lc4);
        float4 bv = *reinterpret_cast<const float4*>(Bb + (size_t)(k0+brow)*ldb + c0 + bcol);
        __syncthreads();
        As[lc4+0][lr] = av.x; As[lc4+1][lr] = av.y; As[lc4+2][lr] = av.z; As[lc4+3][lr] = av.w;
        *reinterpret_cast<float4*>(&Bs[brow][bcol]) = bv;
        __syncthreads();
        #pragma unroll
        for (int kk = 0; kk < 16; ++kk) {
            float4 a4 = *reinterpret_cast<const float4*>(&As[kk][ty*4]);
            float4 b4 = *reinterpret_cast<const float4*>(&Bs[kk][tx*4]);
            float a[4] = {a4.x, a4.y, a4.z, a4.w};
            float bb[4] = {b4.x, b4.y, b4.z, b4.w};
            #pragma unroll
            for (int i = 0; i < 4; ++i)
                #pragma unroll
                for (int j = 0; j < 4; ++j)
                    acc[i][j] += a[i] * bb[j];
        }
    }
}

// --------- generic batched n x n GEMM: C = alpha*alphav[b]*A@B + beta*I + gamma*Cin ---------
__global__ void gemm_kernel(const float* __restrict__ A, int lda, long long sA,
                            const float* __restrict__ B, int ldb, long long sB,
                            float* __restrict__ C, int ldc, long long sC,
                            const float* __restrict__ Cin, int ldcin, long long sCin,
                            const float* __restrict__ alphav,
                            int n, float alpha, float beta, float gamma)
{
    int b  = blockIdx.z;
    int r0 = blockIdx.x * 64, c0 = blockIdx.y * 64;
    int t  = threadIdx.x;
    int tx = t & 15, ty = t >> 4;
    __shared__ float As[16][68];
    __shared__ float Bs[16][68];
    float acc[4][4] = {};
    tile64(A + (size_t)b*sA, lda, B + (size_t)b*sB, ldb, n, r0, c0, t, As, Bs, acc);
    float al = alpha * (alphav ? alphav[b] : 1.0f);
    float* Cb = C + (size_t)b * sC;
    #pragma unroll
    for (int i = 0; i < 4; ++i) {
        int r = r0 + ty*4 + i;
        #pragma unroll
        for (int j = 0; j < 4; ++j) {
            int c = c0 + tx*4 + j;
            float v = al * acc[i][j];
            if (beta != 0.0f && r == c) v += beta;
            if (gamma != 0.0f) v += gamma * Cin[(size_t)b*sCin + (size_t)r*ldcin + c];
            Cb[(size_t)r*ldc + c] = v;
        }
    }
}

// ---------------- NS pair update: Yn = Y@W, Zn = W@Z in one launch ----------------
__global__ void ns_pair_kernel(const float* __restrict__ Y, const float* __restrict__ Z,
                               const float* __restrict__ W,
                               float* __restrict__ Yn, float* __restrict__ Zn)
{
    int bz = blockIdx.z;
    int b = bz >> 1, which = bz & 1;
    const float* A = which ? W + (size_t)b*CC : Y + (size_t)b*CC;
    const float* B = which ? Z + (size_t)b*CC : W + (size_t)b*CC;
    float*       C = which ? Zn + (size_t)b*CC : Yn + (size_t)b*CC;
    int r0 = blockIdx.x * 64, c0 = blockIdx.y * 64;
    int t  = threadIdx.x;
    int tx = t & 15, ty = t >> 4;
    __shared__ float As[16][68];
    __shared__ float Bs[16][68];
    float acc[4][4] = {};
    tile64(A, 256, B, 256, 256, r0, c0, t, As, Bs, acc);
    #pragma unroll
    for (int i = 0; i < 4; ++i)
        #pragma unroll
        for (int j = 0; j < 4; ++j)
            C[(size_t)(r0+ty*4+i)*256 + c0+tx*4+j] = acc[i][j];
}

// ------- strict-lower-triangle partial sums of RAW Z (scaling folded in later) -------
__global__ void tex_partial_kernel(const float* __restrict__ Zf,
                                   float* __restrict__ tsum, float* __restrict__ tsq)
{
    int bx = blockIdx.x;           // 0..255
    int b = bx >> 5, chunk = bx & 31;
    const float* w = Zf + (size_t)b * CC;
    int t = threadIdx.x;
    int base = chunk * 2048;
    float sum = 0.f, sq = 0.f;
    #pragma unroll
    for (int k = 0; k < 8; ++k) {
        int flat = base + k*256 + t;
        int i = flat >> 8, j = flat & 255;
        if (i > j) {
            float v = w[flat];
            sum += v; sq += v * v;
        }
    }
    __shared__ float s1[256], s2[256];
    s1[t] = sum; s2[t] = sq;
    __syncthreads();
    for (int st = 128; st > 0; st >>= 1) {
        if (t < st) { s1[t] += s1[t+st]; s2[t] += s2[t+st]; }
        __syncthreads();
    }
    if (t == 0) {
        atomicAdd(&tsum[b], s1[0]);
        atomicAdd(&tsq[b],  s2[0]);
    }
}

// ------- assemble wm_s (diag from wm = scv*Z); finalize stats inline -------
__global__ void assemble_kernel(const float* __restrict__ Zf, const float* __restrict__ scv,
                                const float* __restrict__ eps,
                                const float* __restrict__ tsum, const float* __restrict__ tsq,
                                float* __restrict__ wms)
{
    size_t idx = (size_t)blockIdx.x * 256 + threadIdx.x;
    int b  = (int)(idx >> 16);
    int ij = (int)(idx & 65535);
    int i = ij >> 8, j = ij & 255;
    float s = scv[b];
    float v;
    if (i == j) {
        v = Zf[idx] * s;
    } else {
        float sum = tsum[b] * s;
        float sq  = tsq[b] * s * s;
        float m = sum / 32640.0f;
        float var = (sq - 2.0f*m*sum + m*m*65536.0f) / 32640.0f;
        float sd = sqrtf(fmaxf(var, 0.0f));
        int lo = min(i, j), hi = max(i, j);
        v = m + 10.0f * sd * eps[(size_t)b*CC + (size_t)lo*256 + hi];
    }
    wms[idx] = v;
}

// ---- 128x128 blocked Gauss-Jordan inverse; panel factorization in ONE WAVE's
// registers (no LDS/barriers in the serial chain). Lane l owns panel rows l, l+64
// (16 panel cols + 16 G cols in regs). Pivot select: packed key (|v| bits | row)
// + 6 shfl_xor max levels. Pivot row broadcast via dynamic __shfl. Trailing
// rank-16 update A += G*R across all 256 threads in registers (as r5). ----
__global__ __launch_bounds__(256, 1)
void gj_inv128_kernel(const float* __restrict__ Ain, int lda, long long sA,
                      float* __restrict__ Out, int ldo, long long sO)
{
    __shared__ float Pnl[128][17];
    __shared__ float Gl[128][17];
    __shared__ float Rs[NBGJ][256];
    __shared__ int   pivots[NBGJ];
    __shared__ int   rowdest[128];

    int b = blockIdx.x;
    int t = threadIdx.x;          // 0..255
    int q = t & 15;               // col ownership: cols {q, q+16, ..., q+240}
    int rg = t >> 4;              // rows rg*8 .. rg*8+7
    int lane = t & 63;
    const float* Ab = Ain + (size_t)b * sA;

    float Areg[8][16];
    #pragma unroll
    for (int rr = 0; rr < 8; ++rr) {
        int r = rg*8 + rr;
        #pragma unroll
        for (int cc = 0; cc < 16; ++cc) {
            int c = q + cc*16;
            Areg[rr][cc] = (c < 128) ? Ab[(size_t)r*lda + c]
                                     : ((c - 128 == r) ? 1.0f : 0.0f);
        }
    }
    // wave-0 persistent pivot bookkeeping (registers)
    int used0 = 0, used1 = 0, dest0 = 0, dest1 = 0, pvkeep = 0;

    for (int pb = 0; pb < 8; ++pb) {
        // dump panel cols (global cols pb*16+q) into Pnl[:, q]
        #pragma unroll
        for (int rr = 0; rr < 8; ++rr) {
            float val = 0.f;
            #pragma unroll
            for (int cc = 0; cc < 16; ++cc)
                if (cc == pb) val = Areg[rr][cc];
            Pnl[rg*8 + rr][q] = val;
        }
        __syncthreads();

        if (t < 64) {
            float pan0[16], pan1[16], g0[16], g1[16];
            #pragma unroll
            for (int cc = 0; cc < 16; ++cc) {
                pan0[cc] = Pnl[lane][cc];
                pan1[cc] = Pnl[lane + 64][cc];
                g0[cc] = 0.f; g1[cc] = 0.f;
            }
            #pragma unroll
            for (int j = 0; j < NBGJ; ++j) {
                // ---- pivot select: max |pan[j]| over unused rows (packed key) ----
                unsigned k0 = used0 ? 0u :
                    ((__float_as_uint(fabsf(pan0[j])) & 0xFFFFFF80u) | (unsigned)lane);
                unsigned k1 = used1 ? 0u :
                    ((__float_as_uint(fabsf(pan1[j])) & 0xFFFFFF80u) | (unsigned)(lane + 64));
                unsigned k = k0 > k1 ? k0 : k1;
                #pragma unroll
                for (int m = 32; m; m >>= 1) {
                    unsigned ok = __shfl_xor(k, m);
                    if (ok > k) k = ok;
                }
                int p = (int)(k & 127u);          // uniform
                int srcl = p & 63, hi = p >> 6;
                // ---- broadcast pivot rows (panel + G cols < j) ----
                float pj[16];
                #pragma unroll
                for (int cc = 0; cc < 16; ++cc) {
                    float tmp = hi ? pan1[cc] : pan0[cc];
                    pj[cc] = __shfl(tmp, srcl);
                }
                float gj[16];
                #pragma unroll
                for (int cc = 0; cc < 16; ++cc) {
                    if (cc < j) {
                        float tg = hi ? g1[cc] : g0[cc];
                        gj[cc] = __shfl(tg, srcl);
                    }
                }
                float rp = 1.0f / pj[j];
                int isp0 = (lane == srcl) && (hi == 0);
                int isp1 = (lane == srcl) && (hi == 1);
                float v0 = isp0 ? (rp - 1.0f) : (-pan0[j] * rp);
                float v1 = isp1 ? (rp - 1.0f) : (-pan1[j] * rp);
                #pragma unroll
                for (int cc = 0; cc < 16; ++cc) {
                    pan0[cc] = fmaf(v0, pj[cc], pan0[cc]);
                    pan1[cc] = fmaf(v1, pj[cc], pan1[cc]);
                    if (cc < j) {
                        g0[cc] = fmaf(v0, gj[cc], g0[cc]);
                        g1[cc] = fmaf(v1, gj[cc], g1[cc]);
                    }
                }
                g0[j] = v0; g1[j] = v1;
                if (isp0) { used0 = 1; dest0 = pb*NBGJ + j; }
                if (isp1) { used1 = 1; dest1 = pb*NBGJ + j; }
                if (lane == j) pvkeep = p;
            }
            // export composed operator G and pivot order
            #pragma unroll
            for (int cc = 0; cc < 16; ++cc) {
                Gl[lane][cc]      = g0[cc];
                Gl[lane + 64][cc] = g1[cc];
            }
            if (lane < NBGJ) pivots[lane] = pvkeep;
        }
        __syncthreads();

        // gather OLD pivot rows (pre-panel register values) into Rs
        for (int j = 0; j < NBGJ; ++j) {
            int p = pivots[j];
            if ((p >> 3) == rg) {
                #pragma unroll
                for (int rr = 0; rr < 8; ++rr)
                    if ((p & 7) == rr) {
                        #pragma unroll
                        for (int cc = 0; cc < 16; ++cc)
                            Rs[j][q + cc*16] = Areg[rr][cc];
                    }
            }
        }
        __syncthreads();

        // trailing rank-16 update: A[r,c] += sum_j G[r,j] * R[j,c]
        #pragma unroll
        for (int j = 0; j < NBGJ; ++j) {
            float rv[16];
            #pragma unroll
            for (int cc = 0; cc < 16; ++cc) rv[cc] = Rs[j][q + cc*16];
            #pragma unroll
            for (int rr = 0; rr < 8; ++rr) {
                float g = Gl[rg*8 + rr][j];
                #pragma unroll
                for (int cc = 0; cc < 16; ++cc)
                    Areg[rr][cc] = fmaf(g, rv[cc], Areg[rr][cc]);
            }
        }
        __syncthreads();
    }

    if (t < 64) { rowdest[lane] = dest0; rowdest[lane + 64] = dest1; }
    __syncthreads();

    float* Ob = Out + (size_t)b * sO;
    #pragma unroll
    for (int rr = 0; rr < 8; ++rr) {
        int r = rg*8 + rr;
        int dest = rowdest[r];
        #pragma unroll
        for (int cc = 8; cc < 16; ++cc) {
            int c = q + cc*16;            // 128..255
            Ob[(size_t)dest*ldo + (c - 128)] = Areg[rr][cc];
        }
    }
}

// ---------------- M21 = M12^T (batched 128x128 transpose, In/Out ld=256) ----------------
__global__ void transpose128_kernel(const float* __restrict__ In, float* __restrict__ Outp)
{
    __shared__ float tile[16][17];
    int b = blockIdx.z;
    int r0 = blockIdx.y * 16, c0 = blockIdx.x * 16;
    int t = threadIdx.x;
    int tx = t & 15, ty = t >> 4;
    tile[ty][tx] = In[(size_t)b*CC + (size_t)(r0+ty)*256 + c0+tx];
    __syncthreads();
    Outp[(size_t)b*CC + (size_t)(c0+ty)*256 + r0+tx] = tile[tx][ty];
}

// ------- fused: target-pool GEMM (M @ (p-mean)) + upsample + clip + HH + write out -------
__global__ void target_kernel(const float* __restrict__ M, const float* __restrict__ p,
                              const float* __restrict__ mean, const float* __restrict__ x,
                              const unsigned int* __restrict__ mm, float* __restrict__ out)
{
    int b  = blockIdx.z;
    int c0 = blockIdx.x * 64;     // channel block
    int ph = blockIdx.y;          // pooled row
    int h0 = ph * 64;
    int t  = threadIdx.x;
    int tx = t & 15, ty = t >> 4;
    __shared__ float As[16][68];
    __shared__ float Bs[16][68];
    __shared__ float accS[64][66];
    const float* Mb = M + (size_t)b * CC;
    const float* pb = p + (size_t)b * C_DIM * PHW;
    const float* mb = mean + b * C_DIM;
    int lr   = t >> 2;
    int lc4  = (t & 3) * 4;
    int brow = t >> 4;
    int bcol = (t & 15) * 4;
    float acc[4][4] = {};
    for (int k0 = 0; k0 < C_DIM; k0 += 16) {
        float4 av = *reinterpret_cast<const float4*>(Mb + (size_t)(c0+lr)*C_DIM + k0 + lc4);
        float  bm = mb[k0 + brow];
        float4 bv = *reinterpret_cast<const float4*>(pb + (size_t)(k0+brow)*PHW + h0 + bcol);
        bv.x -= bm; bv.y -= bm; bv.z -= bm; bv.w -= bm;
        __syncthreads();
        As[lc4+0][lr] = av.x; As[lc4+1][lr] = av.y; As[lc4+2][lr] = av.z; As[lc4+3][lr] = av.w;
        *reinterpret_cast<float4*>(&Bs[brow][bcol]) = bv;
        __syncthreads();
        #pragma unroll
        for (int kk = 0; kk < 16; ++kk) {
            float4 a4 = *reinterpret_cast<const float4*>(&As[kk][ty*4]);
            float4 b4 = *reinterpret_cast<const float4*>(&Bs[kk][tx*4]);
            float a[4] = {a4.x, a4.y, a4.z, a4.w};
            float bb[4] = {b4.x, b4.y, b4.z, b4.w};
            #pragma unroll
            for (int i = 0; i < 4; ++i)
                #pragma unroll
                for (int j = 0; j < 4; ++j)
                    acc[i][j] += a[i] * bb[j];
        }
    }
    __syncthreads();
    #pragma unroll
    for (int i = 0; i < 4; ++i)
        *reinterpret_cast<float4*>(&accS[ty*4+i][tx*4]) =
            make_float4(acc[i][0], acc[i][1], acc[i][2], acc[i][3]);
    __syncthreads();
    float mn = fdec(mm[0]);
    float mx = fdec(mm[1]);
    int lane_ch = t >> 5;           // 0..7
    int col4 = (t & 31) * 4;        // 4 output cols = 2 pooled pixels
    int pw2 = (t & 31) * 2;
    #pragma unroll
    for (int cc8 = 0; cc8 < 64; cc8 += 8) {
        int ch  = cc8 + lane_ch;
        int gch = c0 + ch;
        float me = mb[gch];
        float2 av = *reinterpret_cast<const float2*>(&accS[ch][pw2]);
        float t0 = fminf(fmaxf(av.x + me, mn), mx);
        float t1 = fminf(fmaxf(av.y + me, mn), mx);
        float2 pv = *reinterpret_cast<const float2*>(
            pb + (size_t)gch * PHW + h0 + pw2);
        size_t xbase = (((size_t)b * C_DIM + gch) * H_DIM + 2*ph) * W_DIM + col4;
        #pragma unroll
        for (int row = 0; row < 2; ++row) {
            float4 xv = *reinterpret_cast<const float4*>(x + xbase + row*W_DIM);
            float4 o;
            o.x = xv.x - pv.x + t0;
            o.y = xv.y - pv.x + t0;
            o.z = xv.z - pv.y + t1;
            o.w = xv.w - pv.y + t1;
            *reinterpret_cast<float4*>(out + xbase + row*W_DIM) = o;
        }
    }
}

extern "C" void kernel_launch(void* const* d_in, const int* in_sizes, int n_in,
                              void* d_out, int out_size, void* d_ws, size_t ws_size,
                              hipStream_t stream)
{
    const float* x   = (const float*)d_in[0];
    const float* eps = (const float*)d_in[1];
    float* out = (float*)d_out;
    float* w = (float*)d_ws;

    size_t o = 0;
    float* p    = w + o; o += (size_t)N_B * C_DIM * PHW;  // 8,388,608
    float* bufA = w + o; o += (size_t)N_B * CC;  // wms
    float* bufY = w + o; o += (size_t)N_B * CC;
    float* bufZ = w + o; o += (size_t)N_B * CC;
    float* bufY2= w + o; o += (size_t)N_B * CC;
    float* bufZ2= w + o; o += (size_t)N_B * CC;
    float* bufW = w + o; o += (size_t)N_B * CC;
    float* bufT = w + o; o += (size_t)N_B * CC;
    float* meanb= w + o; o += N_B * C_DIM;
    float* sqb  = w + o; o += N_B * C_DIM;
    float* cvec = w + o; o += N_B;
    float* scv  = w + o; o += N_B;
    float* tsum = w + o; o += N_B;
    float* tsq  = w + o; o += N_B;
    unsigned int* mmx = (unsigned int*)(w + o); o += 2;

    // aliases (lifetime-disjoint)
    float* wms  = bufA;
    float* covp0 = bufY2, *covp1 = bufZ, *covp2 = bufZ2, *covp3 = bufT;
    float* invA11 = bufW;
    float* T1     = bufW + (size_t)N_B * 128 * 128;
    float* Sm     = bufW + (size_t)N_B * 128 * 128 * 2;
    float* Minv   = bufY2;
    float* Rb     = bufZ;
    float* Minv2  = bufY;
    float* Mm     = bufT;

    hipMemsetAsync(mmx,     0xFF, 4, stream);
    hipMemsetAsync(mmx + 1, 0x00, 4, stream);
    hipMemsetAsync(tsum, 0, 2 * N_B * sizeof(float), stream);   // tsum+tsq

    pool_kernel<<<N_B * C_DIM, 256, 0, stream>>>(x, p, meanb, sqb, mmx);
    cvec_kernel<<<N_B, 256, 0, stream>>>(meanb, sqb, cvec, scv);
    cov_part_kernel<<<dim3(4, 4, N_B*4), 256, 0, stream>>>(p, meanb, covp0, covp1, covp2, covp3);
    combine_kernel<<<2048, 256, 0, stream>>>(covp0, covp1, covp2, covp3, cvec, bufY, bufW);

    const long long S  = (long long)CC;
    const long long Sh = 128LL * 128LL;

    // ---- Newton-Schulz, 4 iterations (e: .5625 -> .193 -> .030 -> 6.7e-4 -> 3.3e-7) ----
    // it1 (Z1 = W0 elementwise, from combine): Y1 = Y0@W0 -> bufY2
    gemm_kernel<<<dim3(4,4,N_B), 256, 0, stream>>>(bufY,256,S, bufW,256,S, bufY2,256,S,
                                                   nullptr,0,0, nullptr, 256, 1.0f, 0.0f, 0.0f);
    // it2: W2 = 1.5I - 0.5*Z1@Y1 -> bufY ; pair: Y2=Y1@W2 -> bufZ, Z2=W2@Z1 -> bufZ2
    gemm_kernel<<<dim3(4,4,N_B), 256, 0, stream>>>(bufW,256,S, bufY2,256,S, bufY,256,S,
                                                   nullptr,0,0, nullptr, 256, -0.5f, 1.5f, 0.0f);
    ns_pair_kernel<<<dim3(4,4,2*N_B), 256, 0, stream>>>(bufY2, bufW, bufY, bufZ, bufZ2);
    // it3: W3 = f(Z2@Y2) -> bufY2 ; pair: Y3=Y2@W3 -> bufW, Z3=W3@Z2 -> bufY
    gemm_kernel<<<dim3(4,4,N_B), 256, 0, stream>>>(bufZ2,256,S, bufZ,256,S, bufY2,256,S,
                                                   nullptr,0,0, nullptr, 256, -0.5f, 1.5f, 0.0f);
    ns_pair_kernel<<<dim3(4,4,2*N_B), 256, 0, stream>>>(bufZ, bufZ2, bufY2, bufW, bufY);
    // it4: W4 = f(Z3@Y3) -> bufZ ; Z4 = W4@Z3 -> bufZ2 (skip dead Y4)
    gemm_kernel<<<dim3(4,4,N_B), 256, 0, stream>>>(bufY,256,S, bufW,256,S, bufZ,256,S,
                                                   nullptr,0,0, nullptr, 256, -0.5f, 1.5f, 0.0f);
    gemm_kernel<<<dim3(4,4,N_B), 256, 0, stream>>>(bufZ,256,S, bufY,256,S, bufZ2,256,S,
                                                   nullptr,0,0, nullptr, 256, 1.0f, 0.0f, 0.0f);
    // final Z4 (= wm * sqrt(c)) in bufZ2; wm = scv[b]*Z4 folded into consumers

    tex_partial_kernel<<<256, 256, 0, stream>>>(bufZ2, tsum, tsq);
    assemble_kernel<<<2048, 256, 0, stream>>>(bufZ2, scv, eps, tsum, tsq, wms);

    // ---- Schur-complement inverse of wms (2x2 blocks of 128) ----
    gj_inv128_kernel<<<N_B, 256, 0, stream>>>(wms, 256, S, invA11, 128, Sh);
    gemm_kernel<<<dim3(2,2,N_B), 256, 0, stream>>>(invA11,128,Sh, wms+128,256,S, T1,128,Sh,
                                                   nullptr,0,0, nullptr, 128, 1.0f, 0.0f, 0.0f);
    gemm_kernel<<<dim3(2,2,N_B), 256, 0, stream>>>(wms+128*256,256,S, T1,128,Sh, Sm,128,Sh,
                                                   wms+128*256+128,256,S, nullptr, 128, -1.0f, 0.0f, 1.0f);
    gj_inv128_kernel<<<N_B, 256, 0, stream>>>(Sm, 128, Sh, Minv+128*256+128, 256, S);
    gemm_kernel<<<dim3(2,2,N_B), 256, 0, stream>>>(T1,128,Sh, Minv+128*256+128,256,S, Minv+128,256,S,
                                                   nullptr,0,0, nullptr, 128, -1.0f, 0.0f, 0.0f);
    transpose128_kernel<<<dim3(8,8,N_B), 256, 0, stream>>>(Minv+128, Minv+128*256);
    gemm_kernel<<<dim3(2,2,N_B), 256, 0, stream>>>(T1,128,Sh, Minv+128*256,256,S, Minv,256,S,
                                                   invA11,128,Sh, nullptr, 128, -1.0f, 0.0f, 1.0f);
    // ---- one Newton refinement: Minv2 = Minv (2I - wms Minv) ----
    gemm_kernel<<<dim3(4,4,N_B), 256, 0, stream>>>(wms,256,S, Minv,256,S, Rb,256,S,
                                                   nullptr,0,0, nullptr, 256, -1.0f, 2.0f, 0.0f);
    gemm_kernel<<<dim3(4,4,N_B), 256, 0, stream>>>(Minv,256,S, Rb,256,S, Minv2,256,S,
                                                   nullptr,0,0, nullptr, 256, 1.0f, 0.0f, 0.0f);
    // Mm = Minv2 @ wm = scv[b] * (Minv2 @ Z4)
    gemm_kernel<<<dim3(4,4,N_B), 256, 0, stream>>>(Minv2,256,S, bufZ2,256,S, Mm,256,S,
                                                   nullptr,0,0, scv, 256, 1.0f, 0.0f, 0.0f);

    target_kernel<<<dim3(4, 64, N_B), 256, 0, stream>>>(Mm, p, meanb, x, mmx, out);

    (void)in_sizes; (void)n_in; (void)out_size; (void)ws_size;
}